// Round 1
// baseline (1030.612 us; speedup 1.0000x reference)
//
#include <hip/hip_runtime.h>
#include <math.h>

typedef unsigned short u16;
typedef unsigned int   u32;
typedef __attribute__((ext_vector_type(8))) short bf16x8;   // 8 bf16 (4 VGPRs)
typedef __attribute__((ext_vector_type(4))) float f32x4;

#define DEVI static __device__ __forceinline__

// ---- problem dims ----
constexpr int Bb = 4, Ss = 2048, Cc = 1536, Hh = 8, QD = 128, KD = 128, VD = 192;
constexpr int NTOK = Bb * Ss;              // 8192 tokens
constexpr int NQKV = Hh*QD + KD + VD;      // 1344
constexpr int NQKV_PAD = 1408;             // 11 * 128 (padded for GEMM N-tiles)
constexpr float ATTN_SCALE = 0.08838834764831845f;  // 1/sqrt(128), folded into q

// ---- workspace layout (bytes); total ~81 MB ----
constexpr size_t OFF_S1  = 0;                               // f32[C] rms scale
constexpr size_t OFF_B1  = OFF_S1 + Cc*4;                   // f32[C] rms shift
constexpr size_t OFF_S2  = OFF_B1 + Cc*4;                   // f32[C] out-bn scale
constexpr size_t OFF_B2  = OFF_S2 + Cc*4;                   // f32[C] bo*s2+on_b
constexpr size_t OFF_CT  = 24576;                           // cos qk [S][64]
constexpr size_t OFF_ST  = OFF_CT  + (size_t)Ss*64*4;       // sin qk
constexpr size_t OFF_CTV = OFF_ST  + (size_t)Ss*64*4;       // cos v [S][96]
constexpr size_t OFF_STV = OFF_CTV + (size_t)Ss*96*4;       // sin v
constexpr size_t OFF_WQKV= OFF_STV + (size_t)Ss*96*4;       // bf16 [1408][1536]
constexpr size_t OFF_WO  = OFF_WQKV+ (size_t)NQKV_PAD*Cc*2; // bf16 [1536][1536]
constexpr size_t OFF_XN  = OFF_WO  + (size_t)Cc*Cc*2;       // bf16 [8192][1536]; REUSED as attn O
constexpr size_t OFF_QKV = OFF_XN  + (size_t)NTOK*Cc*2;     // bf16 [8192][1344]
constexpr size_t OFF_Q   = OFF_QKV + (size_t)NTOK*NQKV*2;   // bf16 [B][H][S][128] (rope'd, scaled)
constexpr size_t OFF_K   = OFF_Q   + (size_t)NTOK*(Hh*QD)*2;// bf16 [B][S][128]
constexpr size_t OFF_VT  = OFF_K   + (size_t)NTOK*KD*2;     // bf16 [B][192][S]  (V transposed)

DEVI u16 f2b(float f) {            // f32 -> bf16 RTNE
  union { float f; u32 u; } v; v.f = f;
  u32 r = v.u + 0x7FFFu + ((v.u >> 16) & 1u);
  return (u16)(r >> 16);
}
DEVI float b2f(u16 h) {
  union { u32 u; float f; } v; v.u = ((u32)h) << 16;
  return v.f;
}
DEVI void gload16(const void* g, void* l) {   // async global->LDS, 16B/lane
  __builtin_amdgcn_global_load_lds(g, l, 16, 0, 0);
}
DEVI f32x4 mfma16(bf16x8 a, bf16x8 b, f32x4 c) {
  return __builtin_amdgcn_mfma_f32_16x16x32_bf16(a, b, c, 0, 0, 0);
}

// ===== prep: per-channel scales + rope tables =====
__global__ __launch_bounds__(256) void k_prep_small(
    const float* __restrict__ rms_g, const float* __restrict__ rms_b, const float* __restrict__ rms_r,
    const float* __restrict__ on_g,  const float* __restrict__ on_b,  const float* __restrict__ on_r,
    const float* __restrict__ bo, char* __restrict__ ws)
{
  int i = blockIdx.x * 256 + threadIdx.x;
  float* s1 = (float*)(ws + OFF_S1);
  float* b1 = (float*)(ws + OFF_B1);
  float* s2 = (float*)(ws + OFF_S2);
  float* b2 = (float*)(ws + OFF_B2);
  float* ct = (float*)(ws + OFF_CT);
  float* st = (float*)(ws + OFF_ST);
  float* ctv= (float*)(ws + OFF_CTV);
  float* stv= (float*)(ws + OFF_STV);
  if (i < Cc) {
    float a = rsqrtf(rms_r[i] + 1e-6f) * rms_g[i];
    s1[i] = a; b1[i] = rms_b[i];
    float c = rsqrtf(on_r[i] + 1e-6f) * on_g[i];
    s2[i] = c; b2[i] = bo[i]*c + on_b[i];
  }
  int j = i - Cc;
  if (j >= 0 && j < Ss*64) {            // qk tables, half=64
    int s = j >> 6, f = j & 63;
    float invf = expf(-(float)f * (9.210340371976184f / 64.f)); // 10000^(-f/64)
    float ang = (float)s * invf;
    float sn, cs; sincosf(ang, &sn, &cs);
    ct[j] = cs; st[j] = sn;
  }
  int k = j - Ss*64;
  if (k >= 0 && k < Ss*96) {            // v tables, half=96
    int s = k / 96, f = k - s*96;
    float invf = expf(-(float)f * (9.210340371976184f / 96.f));
    float ang = (float)s * invf;
    float sn, cs; sincosf(ang, &sn, &cs);
    ctv[k] = cs; stv[k] = sn;
  }
}

// ===== prep: weights -> bf16 (Wqkv concat + zero-pad rows 1344..1407) =====
__global__ __launch_bounds__(256) void k_prep_w(
    const float* __restrict__ Wq, const float* __restrict__ Wk, const float* __restrict__ Wv,
    const float* __restrict__ Wo, char* __restrict__ ws)
{
  u16* wqkv = (u16*)(ws + OFF_WQKV);
  u16* wo   = (u16*)(ws + OFF_WO);
  const int total1 = NQKV_PAD * Cc;
  const int total2 = Cc * Cc;
  for (int i = blockIdx.x*256 + threadIdx.x; i < total1 + total2; i += gridDim.x*256) {
    if (i < total1) {
      int r = i / Cc, c = i - r*Cc;
      float v = 0.f;
      if (r < 1024)      v = Wq[(size_t)r*Cc + c];
      else if (r < 1152) v = Wk[(size_t)(r-1024)*Cc + c];
      else if (r < 1344) v = Wv[(size_t)(r-1152)*Cc + c];
      wqkv[i] = f2b(v);
    } else {
      int t2 = i - total1;
      wo[t2] = f2b(Wo[t2]);
    }
  }
}

// ===== xn = x*s1 + b1 (rms_batchnorm is elementwise), f32 -> bf16 =====
__global__ __launch_bounds__(256) void k_xn(const float* __restrict__ x, char* __restrict__ ws)
{
  const float* s1 = (const float*)(ws + OFF_S1);
  const float* b1 = (const float*)(ws + OFF_B1);
  u16* xn = (u16*)(ws + OFF_XN);
  int idx = blockIdx.x*256 + threadIdx.x;          // one float4 per thread, exact grid
  float4 xv = ((const float4*)x)[idx];
  int c = (idx % (Cc/4)) * 4;
  u32 lo = (u32)f2b(xv.x*s1[c]   + b1[c])   | ((u32)f2b(xv.y*s1[c+1] + b1[c+1]) << 16);
  u32 hi = (u32)f2b(xv.z*s1[c+2] + b1[c+2]) | ((u32)f2b(xv.w*s1[c+3] + b1[c+3]) << 16);
  ((uint2*)xn)[idx] = make_uint2(lo, hi);
}

// ===== 128x128 BT-GEMM (A[M][K] bf16, B[N][K] bf16), m97 structure =====
// EPI=false: out bf16.  EPI=true: out f32 = acc*s2[col] + b2[col]
template <bool EPI>
__global__ __launch_bounds__(256) void k_gemm_bt(
    const u16* __restrict__ A, const u16* __restrict__ Bw, void* __restrict__ outp,
    int K, int N_out, const float* __restrict__ s2, const float* __restrict__ b2)
{
  __shared__ u16 a_lds[128*32];
  __shared__ u16 b_lds[128*32];
  const int tid = threadIdx.x;
  const int w = tid >> 6, l = tid & 63;
  const int wr = w >> 1, wc = w & 1;
  const int lr = l & 15, lh = l >> 4;
  const int m0 = blockIdx.y * 128, n0 = blockIdx.x * 128;
  f32x4 acc[4][4] = {};
  const u16* pa = A  + (size_t)(m0 + w*16 + (l>>2))*K + (l&3)*8;
  const u16* pb = Bw + (size_t)(n0 + w*16 + (l>>2))*K + (l&3)*8;
  char* al = (char*)a_lds + w*1024;     // wave-uniform LDS dest bases
  char* bl = (char*)b_lds + w*1024;
  const u16* ar = a_lds + (wr*64 + lr)*32 + lh*8;
  const u16* br = b_lds + (wc*64 + lr)*32 + lh*8;
  for (int k0 = 0; k0 < K; k0 += 32) {
    gload16(pa,                al);
    gload16(pa + (size_t)64*K, al + 4096);
    gload16(pb,                bl);
    gload16(pb + (size_t)64*K, bl + 4096);
    pa += 32; pb += 32;
    __syncthreads();                    // drains vmcnt -> staged tiles valid
    bf16x8 af[4], bfr[4];
#pragma unroll
    for (int m = 0; m < 4; m++) af[m]  = *(const bf16x8*)(ar + m*512);
#pragma unroll
    for (int n = 0; n < 4; n++) bfr[n] = *(const bf16x8*)(br + n*512);
#pragma unroll
    for (int m = 0; m < 4; m++)
#pragma unroll
      for (int n = 0; n < 4; n++)
        acc[m][n] = mfma16(af[m], bfr[n], acc[m][n]);
    __syncthreads();                    // all reads done before next stage
  }
  const int r0 = m0 + wr*64 + lh*4;
  const int c0 = n0 + wc*64 + lr;
#pragma unroll
  for (int m = 0; m < 4; m++) {
#pragma unroll
    for (int n = 0; n < 4; n++) {
      int col = c0 + n*16;
      if (col < N_out) {
#pragma unroll
        for (int r = 0; r < 4; r++) {
          size_t o = (size_t)(r0 + m*16 + r) * N_out + col;
          if (EPI) ((float*)outp)[o] = acc[m][n][r] * s2[col] + b2[col];
          else     ((u16*)outp)[o]   = f2b(acc[m][n][r]);
        }
      }
    }
  }
}

// ===== fused LayerNorm + RoPE for q (65536 rows) and k (8192 rows), 1 wave/row =====
__global__ __launch_bounds__(256) void k_lnrope_qk(
    char* __restrict__ ws,
    const float* __restrict__ q_g, const float* __restrict__ q_b,
    const float* __restrict__ k_g, const float* __restrict__ k_b)
{
  const u16* qkv = (const u16*)(ws + OFF_QKV);
  u16* qo = (u16*)(ws + OFF_Q);
  u16* ko = (u16*)(ws + OFF_K);
  const float* ct = (const float*)(ws + OFF_CT);
  const float* st = (const float*)(ws + OFF_ST);
  const int w = threadIdx.x >> 6, l = threadIdx.x & 63;
  const int rid = blockIdx.x*4 + w;
  const u16* src; u16* dst; const float* g; const float* bb; float osc; int s;
  if (rid < NTOK*Hh) {                       // q rows, order t*8+h
    int t = rid >> 3, h = rid & 7;
    s = t & (Ss-1); int b = t >> 11;
    src = qkv + (size_t)t*NQKV + h*QD;
    dst = qo + ((size_t)(b*Hh + h)*Ss + s)*QD;
    g = q_g; bb = q_b; osc = ATTN_SCALE;
  } else {                                   // k rows
    int t = rid - NTOK*Hh;
    s = t & (Ss-1);
    src = qkv + (size_t)t*NQKV + Hh*QD;
    dst = ko + (size_t)t*KD;
    g = k_g; bb = k_b; osc = 1.f;
  }
  u32 pk = *(const u32*)(src + 2*l);         // elems 2l, 2l+1
  float x0 = b2f((u16)(pk & 0xFFFFu)), x1 = b2f((u16)(pk >> 16));
  float sm = x0 + x1, sq = x0*x0 + x1*x1;
#pragma unroll
  for (int off = 1; off < 64; off <<= 1) { sm += __shfl_xor(sm, off); sq += __shfl_xor(sq, off); }
  float mean = sm * (1.f/128.f);
  float var  = sq * (1.f/128.f) - mean*mean;
  float rstd = rsqrtf(var + 1e-5f);
  int d0 = 2*l;
  float y0 = (x0 - mean)*rstd*g[d0]   + bb[d0];
  float y1 = (x1 - mean)*rstd*g[d0+1] + bb[d0+1];
  float z0 = __shfl_xor(y0, 32);             // rope partner (d <-> d+64)
  float z1 = __shfl_xor(y1, 32);
  int f0 = 2*(l & 31);
  float c0 = ct[s*64 + f0],     s0 = st[s*64 + f0];
  float c1 = ct[s*64 + f0 + 1], s1 = st[s*64 + f0 + 1];
  float o0, o1;
  if (l < 32) { o0 = y0*c0 - z0*s0; o1 = y1*c1 - z1*s1; }   // x1*cos - x2*sin
  else        { o0 = z0*s0 + y0*c0; o1 = z1*s1 + y1*c1; }   // x1*sin + x2*cos
  o0 *= osc; o1 *= osc;
  *(u32*)(dst + 2*l) = (u32)f2b(o0) | ((u32)f2b(o1) << 16);
}

// ===== fused LayerNorm + RoPE for v (192 dims), writes V TRANSPOSED [b][d][s] =====
__global__ __launch_bounds__(256) void k_lnrope_v(
    char* __restrict__ ws, const float* __restrict__ v_g, const float* __restrict__ v_b)
{
  const u16* qkv = (const u16*)(ws + OFF_QKV);
  u16* vo = (u16*)(ws + OFF_VT);
  const float* ct = (const float*)(ws + OFF_CTV);
  const float* st = (const float*)(ws + OFF_STV);
  __shared__ float buf[4][192];
  const int w = threadIdx.x >> 6, l = threadIdx.x & 63;
  const int t = blockIdx.x*4 + w;
  const int s = t & (Ss-1), b = t >> 11;
  const u16* src = qkv + (size_t)t*NQKV + Hh*QD + KD;
  float xs[3]; float sm = 0.f, sq = 0.f;
#pragma unroll
  for (int i2 = 0; i2 < 3; i2++) {
    float xv = b2f(src[l + 64*i2]);
    xs[i2] = xv; buf[w][l + 64*i2] = xv;
    sm += xv; sq += xv*xv;
  }
  __threadfence_block();                     // make row visible (same-wave LDS ordering)
#pragma unroll
  for (int off = 1; off < 64; off <<= 1) { sm += __shfl_xor(sm, off); sq += __shfl_xor(sq, off); }
  float mean = sm * (1.f/192.f);
  float var  = sq * (1.f/192.f) - mean*mean;
  float rstd = rsqrtf(var + 1e-5f);
#pragma unroll
  for (int i2 = 0; i2 < 3; i2++) {
    int e = l + 64*i2;
    float val;
    if (e < 96) {
      float x1 = xs[i2], x2 = buf[w][e+96];
      float x1n = (x1-mean)*rstd*v_g[e]    + v_b[e];
      float x2n = (x2-mean)*rstd*v_g[e+96] + v_b[e+96];
      float cs = ct[s*96 + e], sn = st[s*96 + e];
      val = x1n*cs - x2n*sn;
    } else {
      int f = e - 96;
      float x2 = xs[i2], x1 = buf[w][f];
      float x1n = (x1-mean)*rstd*v_g[f] + v_b[f];
      float x2n = (x2-mean)*rstd*v_g[e] + v_b[e];
      float cs = ct[s*96 + f], sn = st[s*96 + f];
      val = x1n*sn + x2n*cs;
    }
    vo[((size_t)b*VD + e)*Ss + s] = f2b(val);
  }
}

// ===== flash attention: QBLK=64 (4 waves x 16 rows), KVB=64, MQA K/V from L2 =====
__global__ __launch_bounds__(256) void k_attn(const char* __restrict__ ws, u16* __restrict__ O)
{
  const u16* qs = (const u16*)(ws + OFF_Q);
  const u16* ks = (const u16*)(ws + OFF_K);
  const u16* vt = (const u16*)(ws + OFF_VT);
  __shared__ u16 p_lds[4][16][72];           // +8 pad: 144B row stride -> 2-way banks
  const int tid = threadIdx.x, w = tid >> 6, l = tid & 63;
  const int lr = l & 15, lh = l >> 4;
  const int bid = blockIdx.x;
  const int qt = bid & 31, h = (bid >> 5) & 7, b = bid >> 8;
  const int q0 = qt*64 + w*16;
  bf16x8 aq[4];
  const u16* qbase = qs + ((size_t)(b*Hh + h)*Ss + q0 + lr)*QD + lh*8;
#pragma unroll
  for (int kk = 0; kk < 4; kk++) aq[kk] = *(const bf16x8*)(qbase + kk*32);
  float mrow[4], sume[4];
#pragma unroll
  for (int r = 0; r < 4; r++) { mrow[r] = -INFINITY; sume[r] = 0.f; }
  f32x4 acc[12] = {};
  const u16* kbase = ks + ((size_t)b*Ss + lr)*KD + lh*8;
  const u16* vbase = vt + ((size_t)b*VD + lr)*Ss + lh*8;
  for (int kv0 = 0; kv0 < Ss; kv0 += 64) {
    f32x4 sv[4];
#pragma unroll
    for (int nt = 0; nt < 4; nt++) {         // S = Q @ K^T  (16x64)
      f32x4 s4 = {};
      const u16* kb = kbase + (size_t)(kv0 + nt*16)*KD;
#pragma unroll
      for (int kk = 0; kk < 4; kk++) {
        bf16x8 bk = *(const bf16x8*)(kb + kk*32);
        s4 = mfma16(aq[kk], bk, s4);
      }
      sv[nt] = s4;
    }
#pragma unroll
    for (int r = 0; r < 4; r++) {            // online softmax, row = lh*4+r
      float mx = fmaxf(fmaxf(sv[0][r], sv[1][r]), fmaxf(sv[2][r], sv[3][r]));
      mx = fmaxf(mx, __shfl_xor(mx, 1));
      mx = fmaxf(mx, __shfl_xor(mx, 2));
      mx = fmaxf(mx, __shfl_xor(mx, 4));
      mx = fmaxf(mx, __shfl_xor(mx, 8));
      float mnew = fmaxf(mrow[r], mx);
      float scl = __expf(mrow[r] - mnew);
      mrow[r] = mnew;
      float e0 = __expf(sv[0][r] - mnew);
      float e1 = __expf(sv[1][r] - mnew);
      float e2 = __expf(sv[2][r] - mnew);
      float e3 = __expf(sv[3][r] - mnew);
      sv[0][r] = e0; sv[1][r] = e1; sv[2][r] = e2; sv[3][r] = e3;
      float sum = e0 + e1 + e2 + e3;
      sum += __shfl_xor(sum, 1);
      sum += __shfl_xor(sum, 2);
      sum += __shfl_xor(sum, 4);
      sum += __shfl_xor(sum, 8);
      sume[r] = sume[r]*scl + sum;
#pragma unroll
      for (int n = 0; n < 12; n++) acc[n][r] *= scl;
    }
    __threadfence_block();                   // WAR vs previous iter's p_lds reads
#pragma unroll
    for (int nt = 0; nt < 4; nt++)           // P (D-layout) -> LDS [row][col] bf16
#pragma unroll
      for (int r = 0; r < 4; r++)
        p_lds[w][lh*4 + r][nt*16 + lr] = f2b(sv[nt][r]);
    __threadfence_block();                   // RAW: P visible before A-frag reads
#pragma unroll
    for (int kk2 = 0; kk2 < 2; kk2++) {      // O += P @ V
      bf16x8 pa = *(const bf16x8*)(&p_lds[w][lr][kk2*32 + lh*8]);
      const u16* vb = vbase + kv0 + kk2*32;
#pragma unroll
      for (int n = 0; n < 12; n++) {
        bf16x8 bv = *(const bf16x8*)(vb + (size_t)n*16*Ss);
        acc[n] = mfma16(pa, bv, acc[n]);
      }
    }
  }
  float inv[4];
#pragma unroll
  for (int r = 0; r < 4; r++) inv[r] = 1.f / sume[r];
#pragma unroll
  for (int n = 0; n < 12; n++) {
#pragma unroll
    for (int r = 0; r < 4; r++) {
      size_t o = ((size_t)b*Ss + q0 + lh*4 + r)*Cc + h*VD + n*16 + lr;
      O[o] = f2b(acc[n][r] * inv[r]);
    }
  }
}

extern "C" void kernel_launch(void* const* d_in, const int* in_sizes, int n_in,
                              void* d_out, int out_size, void* d_ws, size_t ws_size,
                              hipStream_t stream)
{
  const float* x     = (const float*)d_in[0];
  const float* rms_g = (const float*)d_in[1];
  const float* rms_b = (const float*)d_in[2];
  const float* rms_r = (const float*)d_in[3];
  const float* Wq    = (const float*)d_in[4];
  const float* Wk    = (const float*)d_in[5];
  const float* Wv    = (const float*)d_in[6];
  const float* q_g   = (const float*)d_in[7];
  const float* q_b   = (const float*)d_in[8];
  const float* k_g   = (const float*)d_in[9];
  const float* k_b   = (const float*)d_in[10];
  const float* v_g   = (const float*)d_in[11];
  const float* v_b   = (const float*)d_in[12];
  const float* Wo    = (const float*)d_in[13];
  const float* bo    = (const float*)d_in[14];
  const float* on_g  = (const float*)d_in[15];
  const float* on_b  = (const float*)d_in[16];
  const float* on_r  = (const float*)d_in[17];
  char* ws = (char*)d_ws;

  k_prep_small<<<dim3((Cc + Ss*64 + Ss*96) / 256), 256, 0, stream>>>(
      rms_g, rms_b, rms_r, on_g, on_b, on_r, bo, ws);
  k_prep_w<<<dim3(2048), 256, 0, stream>>>(Wq, Wk, Wv, Wo, ws);
  k_xn<<<dim3(NTOK*Cc/4/256), 256, 0, stream>>>(x, ws);
  k_gemm_bt<false><<<dim3(NQKV_PAD/128, NTOK/128), 256, 0, stream>>>(
      (const u16*)(ws + OFF_XN), (const u16*)(ws + OFF_WQKV), (void*)(ws + OFF_QKV),
      Cc, NQKV, nullptr, nullptr);
  k_lnrope_qk<<<dim3((NTOK*Hh + NTOK)/4), 256, 0, stream>>>(ws, q_g, q_b, k_g, k_b);
  k_lnrope_v<<<dim3(NTOK/4), 256, 0, stream>>>(ws, v_g, v_b);
  k_attn<<<dim3(Bb*Hh*(Ss/64)), 256, 0, stream>>>(ws, (u16*)(ws + OFF_XN));
  k_gemm_bt<true><<<dim3(Cc/128, NTOK/128), 256, 0, stream>>>(
      (const u16*)(ws + OFF_XN), (const u16*)(ws + OFF_WO), d_out,
      Cc, Cc, (const float*)(ws + OFF_S2), (const float*)(ws + OFF_B2));
}

// Round 2
// 947.933 us; speedup vs baseline: 1.0872x; 1.0872x over previous
//
#include <hip/hip_runtime.h>
#include <math.h>

typedef unsigned short u16;
typedef unsigned int   u32;
typedef __attribute__((ext_vector_type(8))) short bf16x8;   // 8 bf16 (4 VGPRs)
typedef __attribute__((ext_vector_type(4))) float f32x4;

#define DEVI static __device__ __forceinline__

// ---- problem dims ----
constexpr int Bb = 4, Ss = 2048, Cc = 1536, Hh = 8, QD = 128, KD = 128, VD = 192;
constexpr int NTOK = Bb * Ss;              // 8192 tokens
constexpr int NQKV = Hh*QD + KD + VD;      // 1344
constexpr int NQKV_PAD = 1408;             // 11 * 128 (padded for GEMM N-tiles)
constexpr float ATTN_SCALE = 0.08838834764831845f;  // 1/sqrt(128), folded into q

// ---- workspace layout (bytes); total ~81 MB ----
constexpr size_t OFF_S1  = 0;                               // f32[C] rms scale
constexpr size_t OFF_B1  = OFF_S1 + Cc*4;                   // f32[C] rms shift
constexpr size_t OFF_S2  = OFF_B1 + Cc*4;                   // f32[C] out-bn scale
constexpr size_t OFF_B2  = OFF_S2 + Cc*4;                   // f32[C] bo*s2+on_b
constexpr size_t OFF_CT  = 24576;                           // cos qk [S][64]
constexpr size_t OFF_ST  = OFF_CT  + (size_t)Ss*64*4;       // sin qk
constexpr size_t OFF_CTV = OFF_ST  + (size_t)Ss*64*4;       // cos v [S][96]
constexpr size_t OFF_STV = OFF_CTV + (size_t)Ss*96*4;       // sin v
constexpr size_t OFF_WQKV= OFF_STV + (size_t)Ss*96*4;       // bf16 [1408][1536]
constexpr size_t OFF_WO  = OFF_WQKV+ (size_t)NQKV_PAD*Cc*2; // bf16 [1536][1536]
constexpr size_t OFF_XN  = OFF_WO  + (size_t)Cc*Cc*2;       // bf16 [8192][1536]; REUSED as attn O
constexpr size_t OFF_QKV = OFF_XN  + (size_t)NTOK*Cc*2;     // bf16 [8192][1344]
constexpr size_t OFF_Q   = OFF_QKV + (size_t)NTOK*NQKV*2;   // bf16 [B][H][S][128] (rope'd, scaled)
constexpr size_t OFF_K   = OFF_Q   + (size_t)NTOK*(Hh*QD)*2;// bf16 [B][S][128]
constexpr size_t OFF_VT  = OFF_K   + (size_t)NTOK*KD*2;     // bf16 [B][192][S]  (V transposed)

DEVI u16 f2b(float f) {            // f32 -> bf16 RTNE
  union { float f; u32 u; } v; v.f = f;
  u32 r = v.u + 0x7FFFu + ((v.u >> 16) & 1u);
  return (u16)(r >> 16);
}
DEVI float b2f(u16 h) {
  union { u32 u; float f; } v; v.u = ((u32)h) << 16;
  return v.f;
}
DEVI u32 cvtpk(float lo, float hi) {       // 2 f32 -> packed bf16x2 (RTNE)
  u32 r;
  asm("v_cvt_pk_bf16_f32 %0, %1, %2" : "=v"(r) : "v"(lo), "v"(hi));
  return r;
}
DEVI void gload16(const void* g, void* l) {   // async global->LDS, 16B/lane
  __builtin_amdgcn_global_load_lds(g, l, 16, 0, 0);
}
DEVI f32x4 mfma16(bf16x8 a, bf16x8 b, f32x4 c) {
  return __builtin_amdgcn_mfma_f32_16x16x32_bf16(a, b, c, 0, 0, 0);
}

// ===== prep: per-channel scales + rope tables =====
__global__ __launch_bounds__(256) void k_prep_small(
    const float* __restrict__ rms_g, const float* __restrict__ rms_b, const float* __restrict__ rms_r,
    const float* __restrict__ on_g,  const float* __restrict__ on_b,  const float* __restrict__ on_r,
    const float* __restrict__ bo, char* __restrict__ ws)
{
  int i = blockIdx.x * 256 + threadIdx.x;
  float* s1 = (float*)(ws + OFF_S1);
  float* b1 = (float*)(ws + OFF_B1);
  float* s2 = (float*)(ws + OFF_S2);
  float* b2 = (float*)(ws + OFF_B2);
  float* ct = (float*)(ws + OFF_CT);
  float* st = (float*)(ws + OFF_ST);
  float* ctv= (float*)(ws + OFF_CTV);
  float* stv= (float*)(ws + OFF_STV);
  if (i < Cc) {
    float a = rsqrtf(rms_r[i] + 1e-6f) * rms_g[i];
    s1[i] = a; b1[i] = rms_b[i];
    float c = rsqrtf(on_r[i] + 1e-6f) * on_g[i];
    s2[i] = c; b2[i] = bo[i]*c + on_b[i];
  }
  int j = i - Cc;
  if (j >= 0 && j < Ss*64) {            // qk tables, half=64
    int s = j >> 6, f = j & 63;
    float invf = expf(-(float)f * (9.210340371976184f / 64.f)); // 10000^(-f/64)
    float ang = (float)s * invf;
    float sn, cs; sincosf(ang, &sn, &cs);
    ct[j] = cs; st[j] = sn;
  }
  int k = j - Ss*64;
  if (k >= 0 && k < Ss*96) {            // v tables, half=96
    int s = k / 96, f = k - s*96;
    float invf = expf(-(float)f * (9.210340371976184f / 96.f));
    float ang = (float)s * invf;
    float sn, cs; sincosf(ang, &sn, &cs);
    ctv[k] = cs; stv[k] = sn;
  }
}

// ===== prep: weights -> bf16 (Wqkv concat + zero-pad rows 1344..1407) =====
__global__ __launch_bounds__(256) void k_prep_w(
    const float* __restrict__ Wq, const float* __restrict__ Wk, const float* __restrict__ Wv,
    const float* __restrict__ Wo, char* __restrict__ ws)
{
  u16* wqkv = (u16*)(ws + OFF_WQKV);
  u16* wo   = (u16*)(ws + OFF_WO);
  const int total1 = NQKV_PAD * Cc;
  const int total2 = Cc * Cc;
  for (int i = blockIdx.x*256 + threadIdx.x; i < total1 + total2; i += gridDim.x*256) {
    if (i < total1) {
      int r = i / Cc, c = i - r*Cc;
      float v = 0.f;
      if (r < 1024)      v = Wq[(size_t)r*Cc + c];
      else if (r < 1152) v = Wk[(size_t)(r-1024)*Cc + c];
      else if (r < 1344) v = Wv[(size_t)(r-1152)*Cc + c];
      wqkv[i] = f2b(v);
    } else {
      int t2 = i - total1;
      wo[t2] = f2b(Wo[t2]);
    }
  }
}

// ===== xn = x*s1 + b1 (rms_batchnorm is elementwise), f32 -> bf16 =====
__global__ __launch_bounds__(256) void k_xn(const float* __restrict__ x, char* __restrict__ ws)
{
  const float* s1 = (const float*)(ws + OFF_S1);
  const float* b1 = (const float*)(ws + OFF_B1);
  u16* xn = (u16*)(ws + OFF_XN);
  int idx = blockIdx.x*256 + threadIdx.x;          // one float4 per thread, exact grid
  float4 xv = ((const float4*)x)[idx];
  int c = (idx % (Cc/4)) * 4;
  u32 lo = (u32)f2b(xv.x*s1[c]   + b1[c])   | ((u32)f2b(xv.y*s1[c+1] + b1[c+1]) << 16);
  u32 hi = (u32)f2b(xv.z*s1[c+2] + b1[c+2]) | ((u32)f2b(xv.w*s1[c+3] + b1[c+3]) << 16);
  ((uint2*)xn)[idx] = make_uint2(lo, hi);
}

// ===== 128x128 BT-GEMM (A[M][K] bf16, B[N][K] bf16), m97 structure =====
// EPI=false: out bf16.  EPI=true: out f32 = acc*s2[col] + b2[col]
template <bool EPI>
__global__ __launch_bounds__(256) void k_gemm_bt(
    const u16* __restrict__ A, const u16* __restrict__ Bw, void* __restrict__ outp,
    int K, int N_out, const float* __restrict__ s2, const float* __restrict__ b2)
{
  __shared__ u16 a_lds[128*32];
  __shared__ u16 b_lds[128*32];
  const int tid = threadIdx.x;
  const int w = tid >> 6, l = tid & 63;
  const int wr = w >> 1, wc = w & 1;
  const int lr = l & 15, lh = l >> 4;
  const int m0 = blockIdx.y * 128, n0 = blockIdx.x * 128;
  f32x4 acc[4][4] = {};
  const u16* pa = A  + (size_t)(m0 + w*16 + (l>>2))*K + (l&3)*8;
  const u16* pb = Bw + (size_t)(n0 + w*16 + (l>>2))*K + (l&3)*8;
  char* al = (char*)a_lds + w*1024;     // wave-uniform LDS dest bases
  char* bl = (char*)b_lds + w*1024;
  const u16* ar = a_lds + (wr*64 + lr)*32 + lh*8;
  const u16* br = b_lds + (wc*64 + lr)*32 + lh*8;
  for (int k0 = 0; k0 < K; k0 += 32) {
    gload16(pa,                al);
    gload16(pa + (size_t)64*K, al + 4096);
    gload16(pb,                bl);
    gload16(pb + (size_t)64*K, bl + 4096);
    pa += 32; pb += 32;
    __syncthreads();                    // drains vmcnt -> staged tiles valid
    bf16x8 af[4], bfr[4];
#pragma unroll
    for (int m = 0; m < 4; m++) af[m]  = *(const bf16x8*)(ar + m*512);
#pragma unroll
    for (int n = 0; n < 4; n++) bfr[n] = *(const bf16x8*)(br + n*512);
#pragma unroll
    for (int m = 0; m < 4; m++)
#pragma unroll
      for (int n = 0; n < 4; n++)
        acc[m][n] = mfma16(af[m], bfr[n], acc[m][n]);
    __syncthreads();                    // all reads done before next stage
  }
  const int r0 = m0 + wr*64 + lh*4;
  const int c0 = n0 + wc*64 + lr;
#pragma unroll
  for (int m = 0; m < 4; m++) {
#pragma unroll
    for (int n = 0; n < 4; n++) {
      int col = c0 + n*16;
      if (col < N_out) {
#pragma unroll
        for (int r = 0; r < 4; r++) {
          size_t o = (size_t)(r0 + m*16 + r) * N_out + col;
          if (EPI) ((float*)outp)[o] = acc[m][n][r] * s2[col] + b2[col];
          else     ((u16*)outp)[o]   = f2b(acc[m][n][r]);
        }
      }
    }
  }
}

// ===== fused LayerNorm + RoPE for q (65536 rows) and k (8192 rows), 1 wave/row =====
__global__ __launch_bounds__(256) void k_lnrope_qk(
    char* __restrict__ ws,
    const float* __restrict__ q_g, const float* __restrict__ q_b,
    const float* __restrict__ k_g, const float* __restrict__ k_b)
{
  const u16* qkv = (const u16*)(ws + OFF_QKV);
  u16* qo = (u16*)(ws + OFF_Q);
  u16* ko = (u16*)(ws + OFF_K);
  const float* ct = (const float*)(ws + OFF_CT);
  const float* st = (const float*)(ws + OFF_ST);
  const int w = threadIdx.x >> 6, l = threadIdx.x & 63;
  const int rid = blockIdx.x*4 + w;
  const u16* src; u16* dst; const float* g; const float* bb; float osc; int s;
  if (rid < NTOK*Hh) {                       // q rows, order t*8+h
    int t = rid >> 3, h = rid & 7;
    s = t & (Ss-1); int b = t >> 11;
    src = qkv + (size_t)t*NQKV + h*QD;
    dst = qo + ((size_t)(b*Hh + h)*Ss + s)*QD;
    g = q_g; bb = q_b; osc = ATTN_SCALE;
  } else {                                   // k rows
    int t = rid - NTOK*Hh;
    s = t & (Ss-1);
    src = qkv + (size_t)t*NQKV + Hh*QD;
    dst = ko + (size_t)t*KD;
    g = k_g; bb = k_b; osc = 1.f;
  }
  u32 pk = *(const u32*)(src + 2*l);         // elems 2l, 2l+1
  float x0 = b2f((u16)(pk & 0xFFFFu)), x1 = b2f((u16)(pk >> 16));
  float sm = x0 + x1, sq = x0*x0 + x1*x1;
#pragma unroll
  for (int off = 1; off < 64; off <<= 1) { sm += __shfl_xor(sm, off); sq += __shfl_xor(sq, off); }
  float mean = sm * (1.f/128.f);
  float var  = sq * (1.f/128.f) - mean*mean;
  float rstd = rsqrtf(var + 1e-5f);
  int d0 = 2*l;
  float y0 = (x0 - mean)*rstd*g[d0]   + bb[d0];
  float y1 = (x1 - mean)*rstd*g[d0+1] + bb[d0+1];
  float z0 = __shfl_xor(y0, 32);             // rope partner (d <-> d+64)
  float z1 = __shfl_xor(y1, 32);
  int f0 = 2*(l & 31);
  float c0 = ct[s*64 + f0],     s0 = st[s*64 + f0];
  float c1 = ct[s*64 + f0 + 1], s1 = st[s*64 + f0 + 1];
  float o0, o1;
  if (l < 32) { o0 = y0*c0 - z0*s0; o1 = y1*c1 - z1*s1; }   // x1*cos - x2*sin
  else        { o0 = z0*s0 + y0*c0; o1 = z1*s1 + y1*c1; }   // x1*sin + x2*cos
  o0 *= osc; o1 *= osc;
  *(u32*)(dst + 2*l) = (u32)f2b(o0) | ((u32)f2b(o1) << 16);
}

// ===== fused LayerNorm + RoPE for v (192 dims), writes V TRANSPOSED [b][d][s] =====
__global__ __launch_bounds__(256) void k_lnrope_v(
    char* __restrict__ ws, const float* __restrict__ v_g, const float* __restrict__ v_b)
{
  const u16* qkv = (const u16*)(ws + OFF_QKV);
  u16* vo = (u16*)(ws + OFF_VT);
  const float* ct = (const float*)(ws + OFF_CTV);
  const float* st = (const float*)(ws + OFF_STV);
  __shared__ float buf[4][192];
  const int w = threadIdx.x >> 6, l = threadIdx.x & 63;
  const int t = blockIdx.x*4 + w;
  const int s = t & (Ss-1), b = t >> 11;
  const u16* src = qkv + (size_t)t*NQKV + Hh*QD + KD;
  float xs[3]; float sm = 0.f, sq = 0.f;
#pragma unroll
  for (int i2 = 0; i2 < 3; i2++) {
    float xv = b2f(src[l + 64*i2]);
    xs[i2] = xv; buf[w][l + 64*i2] = xv;
    sm += xv; sq += xv*xv;
  }
  __threadfence_block();                     // make row visible (same-wave LDS ordering)
#pragma unroll
  for (int off = 1; off < 64; off <<= 1) { sm += __shfl_xor(sm, off); sq += __shfl_xor(sq, off); }
  float mean = sm * (1.f/192.f);
  float var  = sq * (1.f/192.f) - mean*mean;
  float rstd = rsqrtf(var + 1e-5f);
#pragma unroll
  for (int i2 = 0; i2 < 3; i2++) {
    int e = l + 64*i2;
    float val;
    if (e < 96) {
      float x1 = xs[i2], x2 = buf[w][e+96];
      float x1n = (x1-mean)*rstd*v_g[e]    + v_b[e];
      float x2n = (x2-mean)*rstd*v_g[e+96] + v_b[e+96];
      float cs = ct[s*96 + e], sn = st[s*96 + e];
      val = x1n*cs - x2n*sn;
    } else {
      int f = e - 96;
      float x2 = xs[i2], x1 = buf[w][f];
      float x1n = (x1-mean)*rstd*v_g[f] + v_b[f];
      float x2n = (x2-mean)*rstd*v_g[e] + v_b[e];
      float cs = ct[s*96 + f], sn = st[s*96 + f];
      val = x1n*sn + x2n*cs;
    }
    vo[((size_t)b*VD + e)*Ss + s] = f2b(val);
  }
}

// ===== flash attention, SWAPPED QK^T (S^T in regs -> lane-local softmax) =====
// QBLK=64 (4 waves x 16 q-rows), KVB=64, MQA K/V straight from L2.
// Lane l: q = lr = l&15 (4 replicas over lh = l>>4).
// S^T tile nt: sv[nt][r] = S[q=lr][kv = kv0 + nt*16 + lh*4 + r].
// PV computes O^T = V^T @ P: acc[n][r] = O[q=lr][vd = n*16 + lh*4 + r].
__global__ __launch_bounds__(256) void k_attn(const char* __restrict__ ws, u16* __restrict__ O)
{
  const u16* qs = (const u16*)(ws + OFF_Q);
  const u16* ks = (const u16*)(ws + OFF_K);
  const u16* vt = (const u16*)(ws + OFF_VT);
  __shared__ u16 p_lds[4][16][72];           // P[q][kv], +8 pad
  const int tid = threadIdx.x, w = tid >> 6, l = tid & 63;
  const int lr = l & 15, lh = l >> 4;
  const int bid = blockIdx.x;
  const int qt = bid & 31, h = (bid >> 5) & 7, b = bid >> 8;
  const int q0 = qt*64 + w*16;
  bf16x8 aq[4];                              // Q[q=q0+lr][kk*32 + lh*8]
  const u16* qbase = qs + ((size_t)(b*Hh + h)*Ss + q0 + lr)*QD + lh*8;
#pragma unroll
  for (int kk = 0; kk < 4; kk++) aq[kk] = *(const bf16x8*)(qbase + kk*32);
  float m = -INFINITY, sume = 0.f;           // per-lane: running max/denom for q=lr
  f32x4 acc[12] = {};
  const u16* kbase = ks + ((size_t)b*Ss + lr)*KD + lh*8;
  const u16* vbase = vt + ((size_t)b*VD + lr)*Ss + lh*8;
  for (int kv0 = 0; kv0 < Ss; kv0 += 64) {
    f32x4 sv[4];
#pragma unroll
    for (int nt = 0; nt < 4; nt++) {         // S^T = K @ Q^T  (64kv x 16q)
      f32x4 s4 = {};
      const u16* kb = kbase + (size_t)(kv0 + nt*16)*KD;
#pragma unroll
      for (int kk = 0; kk < 4; kk++) {
        bf16x8 bk = *(const bf16x8*)(kb + kk*32);
        s4 = mfma16(bk, aq[kk], s4);         // SWAPPED: A=K, B=Q
      }
      sv[nt] = s4;
    }
    // ---- lane-local online softmax (16 kv values per lane, 4 shfls total) ----
    float tmx = fmaxf(fmaxf(sv[0][0], sv[0][1]), fmaxf(sv[0][2], sv[0][3]));
#pragma unroll
    for (int nt = 1; nt < 4; nt++)
      tmx = fmaxf(tmx, fmaxf(fmaxf(sv[nt][0], sv[nt][1]), fmaxf(sv[nt][2], sv[nt][3])));
    tmx = fmaxf(tmx, __shfl_xor(tmx, 16));
    tmx = fmaxf(tmx, __shfl_xor(tmx, 32));
    if (!__all(tmx - m <= 8.f)) {            // T13 defer-max: rescale only when needed
      float mnew = fmaxf(m, tmx);
      float scl = __expf(m - mnew);
      m = mnew;
      sume *= scl;
#pragma unroll
      for (int n = 0; n < 12; n++) acc[n] *= scl;
    }
    float tsum = 0.f;
#pragma unroll
    for (int nt = 0; nt < 4; nt++) {
#pragma unroll
      for (int r = 0; r < 4; r++) {
        float e = __expf(sv[nt][r] - m);
        sv[nt][r] = e; tsum += e;
      }
    }
    tsum += __shfl_xor(tsum, 16);
    tsum += __shfl_xor(tsum, 32);
    sume += tsum;
    __threadfence_block();                   // WAR vs previous iter's p_lds reads
#pragma unroll
    for (int nt = 0; nt < 4; nt++) {         // P[q=lr][kv] -> LDS, packed b32 writes
      u32 w0 = cvtpk(sv[nt][0], sv[nt][1]);
      u32 w1 = cvtpk(sv[nt][2], sv[nt][3]);
      *(u32*)&p_lds[w][lr][nt*16 + lh*4]     = w0;
      *(u32*)&p_lds[w][lr][nt*16 + lh*4 + 2] = w1;
    }
    __threadfence_block();                   // RAW: P visible before B-frag reads
#pragma unroll
    for (int kk2 = 0; kk2 < 2; kk2++) {      // O^T += V^T @ P
      bf16x8 pb = *(const bf16x8*)(&p_lds[w][lr][kk2*32 + lh*8]);
      const u16* vb = vbase + kv0 + kk2*32;
#pragma unroll
      for (int n = 0; n < 12; n++) {
        bf16x8 av = *(const bf16x8*)(vb + (size_t)n*16*Ss);
        acc[n] = mfma16(av, pb, acc[n]);     // A = V^T rows (vd), B = P rows (q)
      }
    }
  }
  float inv = 1.f / sume;
#pragma unroll
  for (int n = 0; n < 12; n++) {             // O[q=lr][vd=n*16+lh*4+r], packed 8B store
    u32 w0 = cvtpk(acc[n][0]*inv, acc[n][1]*inv);
    u32 w1 = cvtpk(acc[n][2]*inv, acc[n][3]*inv);
    size_t o = ((size_t)b*Ss + q0 + lr)*Cc + h*VD + n*16 + lh*4;
    *(uint2*)(O + o) = make_uint2(w0, w1);
  }
}

extern "C" void kernel_launch(void* const* d_in, const int* in_sizes, int n_in,
                              void* d_out, int out_size, void* d_ws, size_t ws_size,
                              hipStream_t stream)
{
  const float* x     = (const float*)d_in[0];
  const float* rms_g = (const float*)d_in[1];
  const float* rms_b = (const float*)d_in[2];
  const float* rms_r = (const float*)d_in[3];
  const float* Wq    = (const float*)d_in[4];
  const float* Wk    = (const float*)d_in[5];
  const float* Wv    = (const float*)d_in[6];
  const float* q_g   = (const float*)d_in[7];
  const float* q_b   = (const float*)d_in[8];
  const float* k_g   = (const float*)d_in[9];
  const float* k_b   = (const float*)d_in[10];
  const float* v_g   = (const float*)d_in[11];
  const float* v_b   = (const float*)d_in[12];
  const float* Wo    = (const float*)d_in[13];
  const float* bo    = (const float*)d_in[14];
  const float* on_g  = (const float*)d_in[15];
  const float* on_b  = (const float*)d_in[16];
  const float* on_r  = (const float*)d_in[17];
  char* ws = (char*)d_ws;

  k_prep_small<<<dim3((Cc + Ss*64 + Ss*96) / 256), 256, 0, stream>>>(
      rms_g, rms_b, rms_r, on_g, on_b, on_r, bo, ws);
  k_prep_w<<<dim3(2048), 256, 0, stream>>>(Wq, Wk, Wv, Wo, ws);
  k_xn<<<dim3(NTOK*Cc/4/256), 256, 0, stream>>>(x, ws);
  k_gemm_bt<false><<<dim3(NQKV_PAD/128, NTOK/128), 256, 0, stream>>>(
      (const u16*)(ws + OFF_XN), (const u16*)(ws + OFF_WQKV), (void*)(ws + OFF_QKV),
      Cc, NQKV, nullptr, nullptr);
  k_lnrope_qk<<<dim3((NTOK*Hh + NTOK)/4), 256, 0, stream>>>(ws, q_g, q_b, k_g, k_b);
  k_lnrope_v<<<dim3(NTOK/4), 256, 0, stream>>>(ws, v_g, v_b);
  k_attn<<<dim3(Bb*Hh*(Ss/64)), 256, 0, stream>>>(ws, (u16*)(ws + OFF_XN));
  k_gemm_bt<true><<<dim3(Cc/128, NTOK/128), 256, 0, stream>>>(
      (const u16*)(ws + OFF_XN), (const u16*)(ws + OFF_WO), d_out,
      Cc, Cc, (const float*)(ws + OFF_S2), (const float*)(ws + OFF_B2));
}

// Round 3
// 387.846 us; speedup vs baseline: 2.6573x; 2.4441x over previous
//
#include <hip/hip_runtime.h>
#include <math.h>

typedef unsigned short u16;
typedef unsigned int   u32;
typedef __attribute__((ext_vector_type(8))) short bf16x8;   // 8 bf16 (4 VGPRs)
typedef __attribute__((ext_vector_type(4))) float f32x4;

#define DEVI static __device__ __forceinline__

// ---- problem dims ----
constexpr int Bb = 4, Ss = 2048, Cc = 1536, Hh = 8, QD = 128, KD = 128, VD = 192;
constexpr int NTOK = Bb * Ss;              // 8192 tokens
constexpr int NQKV = Hh*QD + KD + VD;      // 1344
constexpr int NQKV_PAD = 1408;             // 11 * 128 (padded for GEMM N-tiles)
constexpr float ATTN_SCALE = 0.08838834764831845f;  // 1/sqrt(128), folded into q

// ---- workspace layout (bytes); total ~81 MB ----
constexpr size_t OFF_S1  = 0;                               // f32[C] rms scale
constexpr size_t OFF_B1  = OFF_S1 + Cc*4;                   // f32[C] rms shift
constexpr size_t OFF_S2  = OFF_B1 + Cc*4;                   // f32[C] out-bn scale
constexpr size_t OFF_B2  = OFF_S2 + Cc*4;                   // f32[C] bo*s2+on_b
constexpr size_t OFF_CT  = 24576;                           // cos qk [S][64]
constexpr size_t OFF_ST  = OFF_CT  + (size_t)Ss*64*4;       // sin qk
constexpr size_t OFF_CTV = OFF_ST  + (size_t)Ss*64*4;       // cos v [S][96]
constexpr size_t OFF_STV = OFF_CTV + (size_t)Ss*96*4;       // sin v
constexpr size_t OFF_WQKV= OFF_STV + (size_t)Ss*96*4;       // bf16 [1408][1536]
constexpr size_t OFF_WO  = OFF_WQKV+ (size_t)NQKV_PAD*Cc*2; // bf16 [1536][1536]
constexpr size_t OFF_XN  = OFF_WO  + (size_t)Cc*Cc*2;       // bf16 [8192][1536]; REUSED as attn O
constexpr size_t OFF_QKV = OFF_XN  + (size_t)NTOK*Cc*2;     // bf16 [8192][1344]
constexpr size_t OFF_Q   = OFF_QKV + (size_t)NTOK*NQKV*2;   // bf16 [B][H][S][128] (rope'd, scaled)
constexpr size_t OFF_K   = OFF_Q   + (size_t)NTOK*(Hh*QD)*2;// bf16 [B][S][128]
constexpr size_t OFF_VT  = OFF_K   + (size_t)NTOK*KD*2;     // bf16 [B][192][S]  (V transposed)

DEVI u16 f2b(float f) {            // f32 -> bf16 RTNE
  union { float f; u32 u; } v; v.f = f;
  u32 r = v.u + 0x7FFFu + ((v.u >> 16) & 1u);
  return (u16)(r >> 16);
}
DEVI float b2f(u16 h) {
  union { u32 u; float f; } v; v.u = ((u32)h) << 16;
  return v.f;
}
DEVI u32 cvtpk(float lo, float hi) {       // 2 f32 -> packed bf16x2 (RTNE)
  u32 r;
  asm("v_cvt_pk_bf16_f32 %0, %1, %2" : "=v"(r) : "v"(lo), "v"(hi));
  return r;
}
DEVI void gload16(const void* g, void* l) {   // async global->LDS, 16B/lane
  __builtin_amdgcn_global_load_lds(g, l, 16, 0, 0);
}
DEVI f32x4 mfma16(bf16x8 a, bf16x8 b, f32x4 c) {
  return __builtin_amdgcn_mfma_f32_16x16x32_bf16(a, b, c, 0, 0, 0);
}

// ===== prep: per-channel scales + rope tables =====
__global__ __launch_bounds__(256) void k_prep_small(
    const float* __restrict__ rms_g, const float* __restrict__ rms_b, const float* __restrict__ rms_r,
    const float* __restrict__ on_g,  const float* __restrict__ on_b,  const float* __restrict__ on_r,
    const float* __restrict__ bo, char* __restrict__ ws)
{
  int i = blockIdx.x * 256 + threadIdx.x;
  float* s1 = (float*)(ws + OFF_S1);
  float* b1 = (float*)(ws + OFF_B1);
  float* s2 = (float*)(ws + OFF_S2);
  float* b2 = (float*)(ws + OFF_B2);
  float* ct = (float*)(ws + OFF_CT);
  float* st = (float*)(ws + OFF_ST);
  float* ctv= (float*)(ws + OFF_CTV);
  float* stv= (float*)(ws + OFF_STV);
  if (i < Cc) {
    float a = rsqrtf(rms_r[i] + 1e-6f) * rms_g[i];
    s1[i] = a; b1[i] = rms_b[i];
    float c = rsqrtf(on_r[i] + 1e-6f) * on_g[i];
    s2[i] = c; b2[i] = bo[i]*c + on_b[i];
  }
  int j = i - Cc;
  if (j >= 0 && j < Ss*64) {            // qk tables, half=64
    int s = j >> 6, f = j & 63;
    float invf = expf(-(float)f * (9.210340371976184f / 64.f)); // 10000^(-f/64)
    float ang = (float)s * invf;
    float sn, cs; sincosf(ang, &sn, &cs);
    ct[j] = cs; st[j] = sn;
  }
  int k = j - Ss*64;
  if (k >= 0 && k < Ss*96) {            // v tables, half=96
    int s = k / 96, f = k - s*96;
    float invf = expf(-(float)f * (9.210340371976184f / 96.f));
    float ang = (float)s * invf;
    float sn, cs; sincosf(ang, &sn, &cs);
    ctv[k] = cs; stv[k] = sn;
  }
}

// ===== prep: weights -> bf16 (Wqkv concat + zero-pad rows 1344..1407) =====
__global__ __launch_bounds__(256) void k_prep_w(
    const float* __restrict__ Wq, const float* __restrict__ Wk, const float* __restrict__ Wv,
    const float* __restrict__ Wo, char* __restrict__ ws)
{
  u16* wqkv = (u16*)(ws + OFF_WQKV);
  u16* wo   = (u16*)(ws + OFF_WO);
  const int total1 = NQKV_PAD * Cc;
  const int total2 = Cc * Cc;
  for (int i = blockIdx.x*256 + threadIdx.x; i < total1 + total2; i += gridDim.x*256) {
    if (i < total1) {
      int r = i / Cc, c = i - r*Cc;
      float v = 0.f;
      if (r < 1024)      v = Wq[(size_t)r*Cc + c];
      else if (r < 1152) v = Wk[(size_t)(r-1024)*Cc + c];
      else if (r < 1344) v = Wv[(size_t)(r-1152)*Cc + c];
      wqkv[i] = f2b(v);
    } else {
      int t2 = i - total1;
      wo[t2] = f2b(Wo[t2]);
    }
  }
}

// ===== xn = x*s1 + b1 (rms_batchnorm is elementwise), f32 -> bf16 =====
__global__ __launch_bounds__(256) void k_xn(const float* __restrict__ x, char* __restrict__ ws)
{
  const float* s1 = (const float*)(ws + OFF_S1);
  const float* b1 = (const float*)(ws + OFF_B1);
  u16* xn = (u16*)(ws + OFF_XN);
  int idx = blockIdx.x*256 + threadIdx.x;          // one float4 per thread, exact grid
  float4 xv = ((const float4*)x)[idx];
  int c = (idx % (Cc/4)) * 4;
  u32 lo = (u32)f2b(xv.x*s1[c]   + b1[c])   | ((u32)f2b(xv.y*s1[c+1] + b1[c+1]) << 16);
  u32 hi = (u32)f2b(xv.z*s1[c+2] + b1[c+2]) | ((u32)f2b(xv.w*s1[c+3] + b1[c+3]) << 16);
  ((uint2*)xn)[idx] = make_uint2(lo, hi);
}

// ===== 128x128 BT-GEMM (A[M][K] bf16, B[N][K] bf16), m97 structure =====
// EPI=false: out bf16.  EPI=true: out f32 = acc*s2[col] + b2[col]
template <bool EPI>
__global__ __launch_bounds__(256) void k_gemm_bt(
    const u16* __restrict__ A, const u16* __restrict__ Bw, void* __restrict__ outp,
    int K, int N_out, const float* __restrict__ s2, const float* __restrict__ b2)
{
  __shared__ u16 a_lds[128*32];
  __shared__ u16 b_lds[128*32];
  const int tid = threadIdx.x;
  const int w = tid >> 6, l = tid & 63;
  const int wr = w >> 1, wc = w & 1;
  const int lr = l & 15, lh = l >> 4;
  const int m0 = blockIdx.y * 128, n0 = blockIdx.x * 128;
  f32x4 acc[4][4] = {};
  const u16* pa = A  + (size_t)(m0 + w*16 + (l>>2))*K + (l&3)*8;
  const u16* pb = Bw + (size_t)(n0 + w*16 + (l>>2))*K + (l&3)*8;
  char* al = (char*)a_lds + w*1024;     // wave-uniform LDS dest bases
  char* bl = (char*)b_lds + w*1024;
  const u16* ar = a_lds + (wr*64 + lr)*32 + lh*8;
  const u16* br = b_lds + (wc*64 + lr)*32 + lh*8;
  for (int k0 = 0; k0 < K; k0 += 32) {
    gload16(pa,                al);
    gload16(pa + (size_t)64*K, al + 4096);
    gload16(pb,                bl);
    gload16(pb + (size_t)64*K, bl + 4096);
    pa += 32; pb += 32;
    __syncthreads();                    // drains vmcnt -> staged tiles valid
    bf16x8 af[4], bfr[4];
#pragma unroll
    for (int m = 0; m < 4; m++) af[m]  = *(const bf16x8*)(ar + m*512);
#pragma unroll
    for (int n = 0; n < 4; n++) bfr[n] = *(const bf16x8*)(br + n*512);
#pragma unroll
    for (int m = 0; m < 4; m++)
#pragma unroll
      for (int n = 0; n < 4; n++)
        acc[m][n] = mfma16(af[m], bfr[n], acc[m][n]);
    __syncthreads();                    // all reads done before next stage
  }
  const int r0 = m0 + wr*64 + lh*4;
  const int c0 = n0 + wc*64 + lr;
#pragma unroll
  for (int m = 0; m < 4; m++) {
#pragma unroll
    for (int n = 0; n < 4; n++) {
      int col = c0 + n*16;
      if (col < N_out) {
#pragma unroll
        for (int r = 0; r < 4; r++) {
          size_t o = (size_t)(r0 + m*16 + r) * N_out + col;
          if (EPI) ((float*)outp)[o] = acc[m][n][r] * s2[col] + b2[col];
          else     ((u16*)outp)[o]   = f2b(acc[m][n][r]);
        }
      }
    }
  }
}

// ===== fused LayerNorm + RoPE for q (65536 rows) and k (8192 rows), 1 wave/row =====
__global__ __launch_bounds__(256) void k_lnrope_qk(
    char* __restrict__ ws,
    const float* __restrict__ q_g, const float* __restrict__ q_b,
    const float* __restrict__ k_g, const float* __restrict__ k_b)
{
  const u16* qkv = (const u16*)(ws + OFF_QKV);
  u16* qo = (u16*)(ws + OFF_Q);
  u16* ko = (u16*)(ws + OFF_K);
  const float* ct = (const float*)(ws + OFF_CT);
  const float* st = (const float*)(ws + OFF_ST);
  const int w = threadIdx.x >> 6, l = threadIdx.x & 63;
  const int rid = blockIdx.x*4 + w;
  const u16* src; u16* dst; const float* g; const float* bb; float osc; int s;
  if (rid < NTOK*Hh) {                       // q rows, order t*8+h
    int t = rid >> 3, h = rid & 7;
    s = t & (Ss-1); int b = t >> 11;
    src = qkv + (size_t)t*NQKV + h*QD;
    dst = qo + ((size_t)(b*Hh + h)*Ss + s)*QD;
    g = q_g; bb = q_b; osc = ATTN_SCALE;
  } else {                                   // k rows
    int t = rid - NTOK*Hh;
    s = t & (Ss-1);
    src = qkv + (size_t)t*NQKV + Hh*QD;
    dst = ko + (size_t)t*KD;
    g = k_g; bb = k_b; osc = 1.f;
  }
  u32 pk = *(const u32*)(src + 2*l);         // elems 2l, 2l+1
  float x0 = b2f((u16)(pk & 0xFFFFu)), x1 = b2f((u16)(pk >> 16));
  float sm = x0 + x1, sq = x0*x0 + x1*x1;
#pragma unroll
  for (int off = 1; off < 64; off <<= 1) { sm += __shfl_xor(sm, off); sq += __shfl_xor(sq, off); }
  float mean = sm * (1.f/128.f);
  float var  = sq * (1.f/128.f) - mean*mean;
  float rstd = rsqrtf(var + 1e-5f);
  int d0 = 2*l;
  float y0 = (x0 - mean)*rstd*g[d0]   + bb[d0];
  float y1 = (x1 - mean)*rstd*g[d0+1] + bb[d0+1];
  float z0 = __shfl_xor(y0, 32);             // rope partner (d <-> d+64)
  float z1 = __shfl_xor(y1, 32);
  int f0 = 2*(l & 31);
  float c0 = ct[s*64 + f0],     s0 = st[s*64 + f0];
  float c1 = ct[s*64 + f0 + 1], s1 = st[s*64 + f0 + 1];
  float o0, o1;
  if (l < 32) { o0 = y0*c0 - z0*s0; o1 = y1*c1 - z1*s1; }   // x1*cos - x2*sin
  else        { o0 = z0*s0 + y0*c0; o1 = z1*s1 + y1*c1; }   // x1*sin + x2*cos
  o0 *= osc; o1 *= osc;
  *(u32*)(dst + 2*l) = (u32)f2b(o0) | ((u32)f2b(o1) << 16);
}

// ===== fused LayerNorm + RoPE for v (192 dims), writes V TRANSPOSED [b][d][s] =====
__global__ __launch_bounds__(256) void k_lnrope_v(
    char* __restrict__ ws, const float* __restrict__ v_g, const float* __restrict__ v_b)
{
  const u16* qkv = (const u16*)(ws + OFF_QKV);
  u16* vo = (u16*)(ws + OFF_VT);
  const float* ct = (const float*)(ws + OFF_CTV);
  const float* st = (const float*)(ws + OFF_STV);
  __shared__ float buf[4][192];
  const int w = threadIdx.x >> 6, l = threadIdx.x & 63;
  const int t = blockIdx.x*4 + w;
  const int s = t & (Ss-1), b = t >> 11;
  const u16* src = qkv + (size_t)t*NQKV + Hh*QD + KD;
  float xs[3]; float sm = 0.f, sq = 0.f;
#pragma unroll
  for (int i2 = 0; i2 < 3; i2++) {
    float xv = b2f(src[l + 64*i2]);
    xs[i2] = xv; buf[w][l + 64*i2] = xv;
    sm += xv; sq += xv*xv;
  }
  __threadfence_block();                     // make row visible (same-wave LDS ordering)
#pragma unroll
  for (int off = 1; off < 64; off <<= 1) { sm += __shfl_xor(sm, off); sq += __shfl_xor(sq, off); }
  float mean = sm * (1.f/192.f);
  float var  = sq * (1.f/192.f) - mean*mean;
  float rstd = rsqrtf(var + 1e-5f);
#pragma unroll
  for (int i2 = 0; i2 < 3; i2++) {
    int e = l + 64*i2;
    float val;
    if (e < 96) {
      float x1 = xs[i2], x2 = buf[w][e+96];
      float x1n = (x1-mean)*rstd*v_g[e]    + v_b[e];
      float x2n = (x2-mean)*rstd*v_g[e+96] + v_b[e+96];
      float cs = ct[s*96 + e], sn = st[s*96 + e];
      val = x1n*cs - x2n*sn;
    } else {
      int f = e - 96;
      float x2 = xs[i2], x1 = buf[w][f];
      float x1n = (x1-mean)*rstd*v_g[f] + v_b[f];
      float x2n = (x2-mean)*rstd*v_g[e] + v_b[e];
      float cs = ct[s*96 + f], sn = st[s*96 + f];
      val = x1n*sn + x2n*cs;
    }
    vo[((size_t)b*VD + e)*Ss + s] = f2b(val);
  }
}

// ===== flash attention v3: LDS-staged K/V tiles, swapped QK^T, QBLK=128 =====
// 4 waves x 32 q-rows; KVB=64. K_lds[64][128], V_lds[192][64] staged via
// global_load_lds w=16 with XOR-pre-swizzled SOURCE (rule 21); ds_read with
// the same XOR -> ~conflict-free. Each V/K fragment feeds 2 MFMAs (q-halves).
__global__ __launch_bounds__(256, 2) void k_attn(const char* __restrict__ ws, u16* __restrict__ O)
{
  const u16* qs = (const u16*)(ws + OFF_Q);
  const u16* ks = (const u16*)(ws + OFF_K);
  const u16* vt = (const u16*)(ws + OFF_VT);
  __shared__ u16 k_lds[64*128];              // [kv][d], 256B rows, swizzled
  __shared__ u16 v_lds[192*64];              // [vd][kv], 128B rows, swizzled
  __shared__ u16 p_lds[4][32][72];           // P[q][kv], +8 pad
  const int tid = threadIdx.x, w = tid >> 6, l = tid & 63;
  const int lr = l & 15, lh = l >> 4;
  const int bid0 = blockIdx.x;
  const int sw = (bid0 & 7)*64 + (bid0 >> 3);   // XCD swizzle: each XCD -> one b
  const int qt = sw & 15, h = (sw >> 4) & 7, b = sw >> 7;
  const int q0 = qt*128 + w*32;
  bf16x8 aq[2][4];                           // Q[q = q0+h2*16+lr][kk*32+lh*8]
  const u16* qbase = qs + ((size_t)(b*Hh + h)*Ss + q0 + lr)*QD + lh*8;
#pragma unroll
  for (int h2 = 0; h2 < 2; h2++)
#pragma unroll
    for (int kk = 0; kk < 4; kk++)
      aq[h2][kk] = *(const bf16x8*)(qbase + (size_t)h2*16*QD + kk*32);
  float m[2] = {-INFINITY, -INFINITY}, sume[2] = {0.f, 0.f};
  f32x4 acc[2][12] = {};
  const char* ksrc0 = (const char*)(ks + (size_t)b*Ss*KD);
  const char* vsrc0 = (const char*)(vt + (size_t)b*VD*Ss);
  for (int kv0 = 0; kv0 < Ss; kv0 += 64) {
    // ---- stage K (16KB, contiguous) + V^T (24KB, 128B rows) ----
    {
      const char* ksrc = ksrc0 + (size_t)kv0*KD*2;
#pragma unroll
      for (int r = 0; r < 4; r++) {
        int o = r*4096 + w*1024 + l*16;
        gload16(ksrc + (o ^ (((o>>8)&7)<<4)), (char*)k_lds + r*4096 + w*1024);
      }
#pragma unroll
      for (int r = 0; r < 6; r++) {
        int o = r*4096 + w*1024 + l*16;
        int vd = o >> 7, c = o & 127;
        gload16(vsrc0 + (size_t)vd*(Ss*2) + kv0*2 + (c ^ ((vd&7)<<4)),
                (char*)v_lds + r*4096 + w*1024);
      }
    }
    __syncthreads();                         // drains vmcnt -> tiles valid
    // ---- S^T = K @ Q^T : 64kv x 32q, K frags shared across q-halves ----
    f32x4 sv[2][4] = {};
#pragma unroll
    for (int nt = 0; nt < 4; nt++) {
#pragma unroll
      for (int kk = 0; kk < 4; kk++) {
        int kb = ((nt*16 + lr) << 8) + kk*64 + lh*16;
        kb ^= (lr & 7) << 4;
        bf16x8 bk = *(const bf16x8*)((const char*)k_lds + kb);
        sv[0][nt] = mfma16(bk, aq[0][kk], sv[0][nt]);
        sv[1][nt] = mfma16(bk, aq[1][kk], sv[1][nt]);
      }
    }
    // ---- lane-local online softmax per q-half (T13 defer-max) ----
#pragma unroll
    for (int h2 = 0; h2 < 2; h2++) {
      float tmx = -INFINITY;
#pragma unroll
      for (int nt = 0; nt < 4; nt++)
        tmx = fmaxf(tmx, fmaxf(fmaxf(sv[h2][nt][0], sv[h2][nt][1]),
                               fmaxf(sv[h2][nt][2], sv[h2][nt][3])));
      tmx = fmaxf(tmx, __shfl_xor(tmx, 16));
      tmx = fmaxf(tmx, __shfl_xor(tmx, 32));
      if (!__all(tmx - m[h2] <= 8.f)) {
        float mnew = fmaxf(m[h2], tmx);
        float scl = __expf(m[h2] - mnew);
        m[h2] = mnew; sume[h2] *= scl;
#pragma unroll
        for (int n = 0; n < 12; n++) acc[h2][n] *= scl;
      }
      float tsum = 0.f;
#pragma unroll
      for (int nt = 0; nt < 4; nt++) {
#pragma unroll
        for (int r2 = 0; r2 < 4; r2++) {
          float e = __expf(sv[h2][nt][r2] - m[h2]);
          sv[h2][nt][r2] = e; tsum += e;
        }
      }
      tsum += __shfl_xor(tsum, 16);
      tsum += __shfl_xor(tsum, 32);
      sume[h2] += tsum;
#pragma unroll
      for (int nt = 0; nt < 4; nt++) {       // P -> LDS, packed b32
        u32 w0 = cvtpk(sv[h2][nt][0], sv[h2][nt][1]);
        u32 w1 = cvtpk(sv[h2][nt][2], sv[h2][nt][3]);
        *(u32*)&p_lds[w][h2*16 + lr][nt*16 + lh*4]     = w0;
        *(u32*)&p_lds[w][h2*16 + lr][nt*16 + lh*4 + 2] = w1;
      }
    }
    asm volatile("s_waitcnt lgkmcnt(0)" ::: "memory");  // wave-local P visible
    __builtin_amdgcn_sched_barrier(0);
    // ---- O^T += V^T @ P ; V frags shared across q-halves ----
#pragma unroll
    for (int kk2 = 0; kk2 < 2; kk2++) {
      bf16x8 pb0 = *(const bf16x8*)(&p_lds[w][lr][kk2*32 + lh*8]);
      bf16x8 pb1 = *(const bf16x8*)(&p_lds[w][16 + lr][kk2*32 + lh*8]);
#pragma unroll
      for (int n = 0; n < 12; n++) {
        int vb = ((n*16 + lr) << 7) + kk2*64 + lh*16;
        vb ^= (lr & 7) << 4;
        bf16x8 av = *(const bf16x8*)((const char*)v_lds + vb);
        acc[0][n] = mfma16(av, pb0, acc[0][n]);
        acc[1][n] = mfma16(av, pb1, acc[1][n]);
      }
    }
    __syncthreads();                         // WAR: reads done before next stage
  }
#pragma unroll
  for (int h2 = 0; h2 < 2; h2++) {
    float inv = 1.f / sume[h2];
#pragma unroll
    for (int n = 0; n < 12; n++) {           // O[q][vd], packed 8B store
      u32 w0 = cvtpk(acc[h2][n][0]*inv, acc[h2][n][1]*inv);
      u32 w1 = cvtpk(acc[h2][n][2]*inv, acc[h2][n][3]*inv);
      size_t o = ((size_t)b*Ss + q0 + h2*16 + lr)*Cc + h*VD + n*16 + lh*4;
      *(uint2*)(O + o) = make_uint2(w0, w1);
    }
  }
}

extern "C" void kernel_launch(void* const* d_in, const int* in_sizes, int n_in,
                              void* d_out, int out_size, void* d_ws, size_t ws_size,
                              hipStream_t stream)
{
  const float* x     = (const float*)d_in[0];
  const float* rms_g = (const float*)d_in[1];
  const float* rms_b = (const float*)d_in[2];
  const float* rms_r = (const float*)d_in[3];
  const float* Wq    = (const float*)d_in[4];
  const float* Wk    = (const float*)d_in[5];
  const float* Wv    = (const float*)d_in[6];
  const float* q_g   = (const float*)d_in[7];
  const float* q_b   = (const float*)d_in[8];
  const float* k_g   = (const float*)d_in[9];
  const float* k_b   = (const float*)d_in[10];
  const float* v_g   = (const float*)d_in[11];
  const float* v_b   = (const float*)d_in[12];
  const float* Wo    = (const float*)d_in[13];
  const float* bo    = (const float*)d_in[14];
  const float* on_g  = (const float*)d_in[15];
  const float* on_b  = (const float*)d_in[16];
  const float* on_r  = (const float*)d_in[17];
  char* ws = (char*)d_ws;

  k_prep_small<<<dim3((Cc + Ss*64 + Ss*96) / 256), 256, 0, stream>>>(
      rms_g, rms_b, rms_r, on_g, on_b, on_r, bo, ws);
  k_prep_w<<<dim3(2048), 256, 0, stream>>>(Wq, Wk, Wv, Wo, ws);
  k_xn<<<dim3(NTOK*Cc/4/256), 256, 0, stream>>>(x, ws);
  k_gemm_bt<false><<<dim3(NQKV_PAD/128, NTOK/128), 256, 0, stream>>>(
      (const u16*)(ws + OFF_XN), (const u16*)(ws + OFF_WQKV), (void*)(ws + OFF_QKV),
      Cc, NQKV, nullptr, nullptr);
  k_lnrope_qk<<<dim3((NTOK*Hh + NTOK)/4), 256, 0, stream>>>(ws, q_g, q_b, k_g, k_b);
  k_lnrope_v<<<dim3(NTOK/4), 256, 0, stream>>>(ws, v_g, v_b);
  k_attn<<<dim3(Bb*Hh*(Ss/128)), 256, 0, stream>>>(ws, (u16*)(ws + OFF_XN));
  k_gemm_bt<true><<<dim3(Cc/128, NTOK/128), 256, 0, stream>>>(
      (const u16*)(ws + OFF_XN), (const u16*)(ws + OFF_WO), d_out,
      Cc, Cc, (const float*)(ws + OFF_S2), (const float*)(ws + OFF_B2));
}

// Round 5
// 374.074 us; speedup vs baseline: 2.7551x; 1.0368x over previous
//
#include <hip/hip_runtime.h>
#include <math.h>

typedef unsigned short u16;
typedef unsigned int   u32;
typedef __attribute__((ext_vector_type(8))) short bf16x8;   // 8 bf16 (4 VGPRs)
typedef __attribute__((ext_vector_type(4))) float f32x4;

#define DEVI static __device__ __forceinline__

// ---- problem dims ----
constexpr int Bb = 4, Ss = 2048, Cc = 1536, Hh = 8, QD = 128, KD = 128, VD = 192;
constexpr int NTOK = Bb * Ss;              // 8192 tokens
constexpr int NQKV = Hh*QD + KD + VD;      // 1344
constexpr int NQKV_PAD = 1536;             // padded to 6*256 for 256^2 GEMM tiles
constexpr float ATTN_SCALE = 0.08838834764831845f;  // 1/sqrt(128), folded into q

// ---- workspace layout (bytes); total ~84 MB ----
constexpr size_t OFF_S1  = 0;                               // f32[C] rms scale
constexpr size_t OFF_B1  = OFF_S1 + Cc*4;                   // f32[C] rms shift
constexpr size_t OFF_S2  = OFF_B1 + Cc*4;                   // f32[C] out-bn scale
constexpr size_t OFF_B2  = OFF_S2 + Cc*4;                   // f32[C] bo*s2+on_b
constexpr size_t OFF_CT  = 24576;                           // cos qk [S][64]
constexpr size_t OFF_ST  = OFF_CT  + (size_t)Ss*64*4;       // sin qk
constexpr size_t OFF_CTV = OFF_ST  + (size_t)Ss*64*4;       // cos v [S][96]
constexpr size_t OFF_STV = OFF_CTV + (size_t)Ss*96*4;       // sin v
constexpr size_t OFF_WQKV= OFF_STV + (size_t)Ss*96*4;       // bf16 [1536][1536] (rows>=1344 zero)
constexpr size_t OFF_WO  = OFF_WQKV+ (size_t)NQKV_PAD*Cc*2; // bf16 [1536][1536]
constexpr size_t OFF_XN  = OFF_WO  + (size_t)Cc*Cc*2;       // bf16 [8192][1536]; REUSED as attn O
constexpr size_t OFF_QKV = OFF_XN  + (size_t)NTOK*Cc*2;     // bf16 [8192][1344]
constexpr size_t OFF_Q   = OFF_QKV + (size_t)NTOK*NQKV*2;   // bf16 [B][H][S][128] (rope'd, scaled)
constexpr size_t OFF_K   = OFF_Q   + (size_t)NTOK*(Hh*QD)*2;// bf16 [B][S][128]
constexpr size_t OFF_VT  = OFF_K   + (size_t)NTOK*KD*2;     // bf16 [B][192][S]  (V transposed)

DEVI u16 f2b(float f) {            // f32 -> bf16 RTNE
  union { float f; u32 u; } v; v.f = f;
  u32 r = v.u + 0x7FFFu + ((v.u >> 16) & 1u);
  return (u16)(r >> 16);
}
DEVI float b2f(u16 h) {
  union { u32 u; float f; } v; v.u = ((u32)h) << 16;
  return v.f;
}
DEVI u32 cvtpk(float lo, float hi) {       // 2 f32 -> packed bf16x2 (RTNE)
  u32 r;
  asm("v_cvt_pk_bf16_f32 %0, %1, %2" : "=v"(r) : "v"(lo), "v"(hi));
  return r;
}
DEVI void gload16(const void* g, void* l) {   // async global->LDS, 16B/lane
  __builtin_amdgcn_global_load_lds(g, l, 16, 0, 0);
}
DEVI f32x4 mfma16(bf16x8 a, bf16x8 b, f32x4 c) {
  return __builtin_amdgcn_mfma_f32_16x16x32_bf16(a, b, c, 0, 0, 0);
}
// st-swizzle for [*][32] bf16 tiles (64B rows): spread 16B chunks across the
// 8 groups of the 128B bank cycle.  Involution (flips bits 4,5 from bits 7,8).
DEVI int swz64(int byte) {
  return byte ^ ((((byte>>7)&1)<<4) | (((byte>>8)&1)<<5));
}

// ===== prep: per-channel scales + rope tables =====
__global__ __launch_bounds__(256) void k_prep_small(
    const float* __restrict__ rms_g, const float* __restrict__ rms_b, const float* __restrict__ rms_r,
    const float* __restrict__ on_g,  const float* __restrict__ on_b,  const float* __restrict__ on_r,
    const float* __restrict__ bo, char* __restrict__ ws)
{
  int i = blockIdx.x * 256 + threadIdx.x;
  float* s1 = (float*)(ws + OFF_S1);
  float* b1 = (float*)(ws + OFF_B1);
  float* s2 = (float*)(ws + OFF_S2);
  float* b2 = (float*)(ws + OFF_B2);
  float* ct = (float*)(ws + OFF_CT);
  float* st = (float*)(ws + OFF_ST);
  float* ctv= (float*)(ws + OFF_CTV);
  float* stv= (float*)(ws + OFF_STV);
  if (i < Cc) {
    float a = rsqrtf(rms_r[i] + 1e-6f) * rms_g[i];
    s1[i] = a; b1[i] = rms_b[i];
    float c = rsqrtf(on_r[i] + 1e-6f) * on_g[i];
    s2[i] = c; b2[i] = bo[i]*c + on_b[i];
  }
  int j = i - Cc;
  if (j >= 0 && j < Ss*64) {            // qk tables, half=64
    int s = j >> 6, f = j & 63;
    float invf = expf(-(float)f * (9.210340371976184f / 64.f)); // 10000^(-f/64)
    float ang = (float)s * invf;
    float sn, cs; sincosf(ang, &sn, &cs);
    ct[j] = cs; st[j] = sn;
  }
  int k = j - Ss*64;
  if (k >= 0 && k < Ss*96) {            // v tables, half=96
    int s = k / 96, f = k - s*96;
    float invf = expf(-(float)f * (9.210340371976184f / 96.f));
    float ang = (float)s * invf;
    float sn, cs; sincosf(ang, &sn, &cs);
    ctv[k] = cs; stv[k] = sn;
  }
}

// ===== prep: weights -> bf16 (Wqkv concat + zero-pad rows 1344..1535) =====
__global__ __launch_bounds__(256) void k_prep_w(
    const float* __restrict__ Wq, const float* __restrict__ Wk, const float* __restrict__ Wv,
    const float* __restrict__ Wo, char* __restrict__ ws)
{
  u16* wqkv = (u16*)(ws + OFF_WQKV);
  u16* wo   = (u16*)(ws + OFF_WO);
  const int total1 = NQKV_PAD * Cc;
  const int total2 = Cc * Cc;
  for (int i = blockIdx.x*256 + threadIdx.x; i < total1 + total2; i += gridDim.x*256) {
    if (i < total1) {
      int r = i / Cc, c = i - r*Cc;
      float v = 0.f;
      if (r < 1024)      v = Wq[(size_t)r*Cc + c];
      else if (r < 1152) v = Wk[(size_t)(r-1024)*Cc + c];
      else if (r < 1344) v = Wv[(size_t)(r-1152)*Cc + c];
      wqkv[i] = f2b(v);
    } else {
      int t2 = i - total1;
      wo[t2] = f2b(Wo[t2]);
    }
  }
}

// ===== xn = x*s1 + b1 (rms_batchnorm is elementwise), f32 -> bf16 =====
__global__ __launch_bounds__(256) void k_xn(const float* __restrict__ x, char* __restrict__ ws)
{
  const float* s1 = (const float*)(ws + OFF_S1);
  const float* b1 = (const float*)(ws + OFF_B1);
  u16* xn = (u16*)(ws + OFF_XN);
  int idx = blockIdx.x*256 + threadIdx.x;          // one float4 per thread, exact grid
  float4 xv = ((const float4*)x)[idx];
  int c = (idx % (Cc/4)) * 4;
  u32 lo = (u32)f2b(xv.x*s1[c]   + b1[c])   | ((u32)f2b(xv.y*s1[c+1] + b1[c+1]) << 16);
  u32 hi = (u32)f2b(xv.z*s1[c+2] + b1[c+2]) | ((u32)f2b(xv.w*s1[c+3] + b1[c+3]) << 16);
  ((uint2*)xn)[idx] = make_uint2(lo, hi);
}

// ===== 256x256 BT-GEMM, BK=32, 4-buffer deep pipeline, counted vmcnt =====
// A[M][K] bf16, B[N][K] bf16.  8 waves (2M x 4N), per-wave out 128x64.
// EPI=false: out bf16, cols >= N_store masked.  EPI=true: f32 acc*s2+b2.
template <bool EPI>
__global__ __launch_bounds__(512, 2) void k_gemm256(
    const u16* __restrict__ A, const u16* __restrict__ Bw, void* __restrict__ outp,
    int K, int N_store, const float* __restrict__ s2, const float* __restrict__ b2)
{
  __shared__ u16 tiles[4][2][8192];   // [buf][A|B][256 rows x 32 k], swizzled, 128 KiB
  const int tid = threadIdx.x;
  const int wid = tid >> 6, l = tid & 63;
  const int lr = l & 15, lh = l >> 4;
  const int wr = wid >> 2, wc = wid & 3;
  // bijective XCD chunk swizzle (nwg = 192 = 8 * 24)
  const int id  = blockIdx.x + gridDim.x * blockIdx.y;
  const int cpx = (gridDim.x * gridDim.y) >> 3;
  const int sw  = (id & 7) * cpx + (id >> 3);
  const int by  = sw / gridDim.x;
  const int bx  = sw - by * gridDim.x;
  const int m0 = by * 256, n0 = bx * 256;

  const size_t Kb = (size_t)K * 2;
  const char* aBase = (const char*)(A  + (size_t)m0 * K);
  const char* bBase = (const char*)(Bw + (size_t)n0 * K);
  // staging source offsets (pre-swizzled global, linear LDS dest — rule 21)
  const int o0    = wid*1024 + l*16;
  const int sfl   = swz64(o0);
  const size_t srowb = (size_t)(sfl >> 6) * Kb;   // rows 0..127 (part1 = +128 rows)
  const int scolb = sfl & 63;
  // fragment read offsets (loop-invariant)
  int aoff[8], boff[4];
#pragma unroll
  for (int mi = 0; mi < 8; mi++) aoff[mi] = swz64((wr*128 + mi*16 + lr)*64 + lh*16);
#pragma unroll
  for (int ni = 0; ni < 4; ni++) boff[ni] = swz64((wc*64  + ni*16 + lr)*64 + lh*16);

  f32x4 acc[8][4] = {};
  const int NT = K >> 5;               // 48

#define STAGE(t) {                                                        \
    char* la_ = (char*)tiles[(t) & 3][0] + wid*1024;                      \
    char* lb_ = (char*)tiles[(t) & 3][1] + wid*1024;                      \
    const char* ga_ = aBase + srowb + (size_t)(t)*64 + scolb;             \
    const char* gb_ = bBase + srowb + (size_t)(t)*64 + scolb;             \
    gload16(ga_,            la_);                                         \
    gload16(ga_ + 128*Kb,   la_ + 8192);                                  \
    gload16(gb_,            lb_);                                         \
    gload16(gb_ + 128*Kb,   lb_ + 8192);                                  \
  }

  STAGE(0); STAGE(1); STAGE(2);
  for (int t = 0; t < NT; ++t) {
    if (t + 3 < NT) STAGE(t + 3);
    asm volatile("s_waitcnt vmcnt(12)" ::: "memory");  // tile t confirmed; 3 tiles in flight
    __builtin_amdgcn_s_barrier();
    const char* la = (const char*)tiles[t & 3][0];
    const char* lb = (const char*)tiles[t & 3][1];
    bf16x8 af[8], bfr[4];
#pragma unroll
    for (int mi = 0; mi < 8; mi++) af[mi]  = *(const bf16x8*)(la + aoff[mi]);
#pragma unroll
    for (int ni = 0; ni < 4; ni++) bfr[ni] = *(const bf16x8*)(lb + boff[ni]);
    __builtin_amdgcn_s_setprio(1);
#pragma unroll
    for (int mi = 0; mi < 8; mi++)
#pragma unroll
      for (int ni = 0; ni < 4; ni++)
        acc[mi][ni] = mfma16(af[mi], bfr[ni], acc[mi][ni]);
    __builtin_amdgcn_s_setprio(0);
    asm volatile("s_waitcnt lgkmcnt(0)" ::: "memory"); // frag reads landed before flip
    __builtin_amdgcn_s_barrier();
  }
#undef STAGE

  const int r0 = m0 + wr*128 + lh*4;
  const int c0 = n0 + wc*64 + lr;
#pragma unroll
  for (int mi = 0; mi < 8; mi++) {
#pragma unroll
    for (int ni = 0; ni < 4; ni++) {
      int col = c0 + ni*16;
      if (col < N_store) {
#pragma unroll
        for (int r = 0; r < 4; r++) {
          size_t o = (size_t)(r0 + mi*16 + r) * N_store + col;
          if (EPI) ((float*)outp)[o] = acc[mi][ni][r] * s2[col] + b2[col];
          else     ((u16*)outp)[o]   = f2b(acc[mi][ni][r]);
        }
      }
    }
  }
}

// ===== fused LayerNorm + RoPE for q (65536 rows) and k (8192 rows), 1 wave/row =====
__global__ __launch_bounds__(256) void k_lnrope_qk(
    char* __restrict__ ws,
    const float* __restrict__ q_g, const float* __restrict__ q_b,
    const float* __restrict__ k_g, const float* __restrict__ k_b)
{
  const u16* qkv = (const u16*)(ws + OFF_QKV);
  u16* qo = (u16*)(ws + OFF_Q);
  u16* ko = (u16*)(ws + OFF_K);
  const float* ct = (const float*)(ws + OFF_CT);
  const float* st = (const float*)(ws + OFF_ST);
  const int w = threadIdx.x >> 6, l = threadIdx.x & 63;
  const int rid = blockIdx.x*4 + w;
  const u16* src; u16* dst; const float* g; const float* bb; float osc; int s;
  if (rid < NTOK*Hh) {                       // q rows, order t*8+h
    int t = rid >> 3, h = rid & 7;
    s = t & (Ss-1); int b = t >> 11;
    src = qkv + (size_t)t*NQKV + h*QD;
    dst = qo + ((size_t)(b*Hh + h)*Ss + s)*QD;
    g = q_g; bb = q_b; osc = ATTN_SCALE;
  } else {                                   // k rows
    int t = rid - NTOK*Hh;
    s = t & (Ss-1);
    src = qkv + (size_t)t*NQKV + Hh*QD;
    dst = ko + (size_t)t*KD;
    g = k_g; bb = k_b; osc = 1.f;
  }
  u32 pk = *(const u32*)(src + 2*l);         // elems 2l, 2l+1
  float x0 = b2f((u16)(pk & 0xFFFFu)), x1 = b2f((u16)(pk >> 16));
  float sm = x0 + x1, sq = x0*x0 + x1*x1;
#pragma unroll
  for (int off = 1; off < 64; off <<= 1) { sm += __shfl_xor(sm, off); sq += __shfl_xor(sq, off); }
  float mean = sm * (1.f/128.f);
  float var  = sq * (1.f/128.f) - mean*mean;
  float rstd = rsqrtf(var + 1e-5f);
  int d0 = 2*l;
  float y0 = (x0 - mean)*rstd*g[d0]   + bb[d0];
  float y1 = (x1 - mean)*rstd*g[d0+1] + bb[d0+1];
  float z0 = __shfl_xor(y0, 32);             // rope partner (d <-> d+64)
  float z1 = __shfl_xor(y1, 32);
  int f0 = 2*(l & 31);
  float c0 = ct[s*64 + f0],     s0 = st[s*64 + f0];
  float c1 = ct[s*64 + f0 + 1], s1 = st[s*64 + f0 + 1];
  float o0, o1;
  if (l < 32) { o0 = y0*c0 - z0*s0; o1 = y1*c1 - z1*s1; }   // x1*cos - x2*sin
  else        { o0 = z0*s0 + y0*c0; o1 = z1*s1 + y1*c1; }   // x1*sin + x2*cos
  o0 *= osc; o1 *= osc;
  *(u32*)(dst + 2*l) = (u32)f2b(o0) | ((u32)f2b(o1) << 16);
}

// ===== fused LayerNorm + RoPE for v (192 dims), writes V TRANSPOSED [b][d][s] =====
__global__ __launch_bounds__(256) void k_lnrope_v(
    char* __restrict__ ws, const float* __restrict__ v_g, const float* __restrict__ v_b)
{
  const u16* qkv = (const u16*)(ws + OFF_QKV);
  u16* vo = (u16*)(ws + OFF_VT);
  const float* ct = (const float*)(ws + OFF_CTV);
  const float* st = (const float*)(ws + OFF_STV);
  __shared__ float buf[4][192];
  const int w = threadIdx.x >> 6, l = threadIdx.x & 63;
  const int t = blockIdx.x*4 + w;
  const int s = t & (Ss-1), b = t >> 11;
  const u16* src = qkv + (size_t)t*NQKV + Hh*QD + KD;
  float xs[3]; float sm = 0.f, sq = 0.f;
#pragma unroll
  for (int i2 = 0; i2 < 3; i2++) {
    float xv = b2f(src[l + 64*i2]);
    xs[i2] = xv; buf[w][l + 64*i2] = xv;
    sm += xv; sq += xv*xv;
  }
  __threadfence_block();                     // make row visible (same-wave LDS ordering)
#pragma unroll
  for (int off = 1; off < 64; off <<= 1) { sm += __shfl_xor(sm, off); sq += __shfl_xor(sq, off); }
  float mean = sm * (1.f/192.f);
  float var  = sq * (1.f/192.f) - mean*mean;
  float rstd = rsqrtf(var + 1e-5f);
#pragma unroll
  for (int i2 = 0; i2 < 3; i2++) {
    int e = l + 64*i2;
    float val;
    if (e < 96) {
      float x1 = xs[i2], x2 = buf[w][e+96];
      float x1n = (x1-mean)*rstd*v_g[e]    + v_b[e];
      float x2n = (x2-mean)*rstd*v_g[e+96] + v_b[e+96];
      float cs = ct[s*96 + e], sn = st[s*96 + e];
      val = x1n*cs - x2n*sn;
    } else {
      int f = e - 96;
      float x2 = xs[i2], x1 = buf[w][f];
      float x1n = (x1-mean)*rstd*v_g[f] + v_b[f];
      float x2n = (x2-mean)*rstd*v_g[e] + v_b[e];
      float cs = ct[s*96 + f], sn = st[s*96 + f];
      val = x1n*sn + x2n*cs;
    }
    vo[((size_t)b*VD + e)*Ss + s] = f2b(val);
  }
}

// ===== flash attention v3: LDS-staged K/V tiles, swapped QK^T, QBLK=128 =====
// 4 waves x 32 q-rows; KVB=64. K_lds[64][128], V_lds[192][64] staged via
// global_load_lds w=16 with XOR-pre-swizzled SOURCE (rule 21); ds_read with
// the same XOR -> ~conflict-free. Each V/K fragment feeds 2 MFMAs (q-halves).
__global__ __launch_bounds__(256, 2) void k_attn(const char* __restrict__ ws, u16* __restrict__ O)
{
  const u16* qs = (const u16*)(ws + OFF_Q);
  const u16* ks = (const u16*)(ws + OFF_K);
  const u16* vt = (const u16*)(ws + OFF_VT);
  __shared__ u16 k_lds[64*128];              // [kv][d], 256B rows, swizzled
  __shared__ u16 v_lds[192*64];              // [vd][kv], 128B rows, swizzled
  __shared__ u16 p_lds[4][32][64];           // P[q][kv], 128B rows, XOR-swizzled
  const int tid = threadIdx.x, w = tid >> 6, l = tid & 63;
  const int lr = l & 15, lh = l >> 4;
  const int bid0 = blockIdx.x;
  const int sw = (bid0 & 7)*64 + (bid0 >> 3);   // XCD swizzle: each XCD -> one b
  const int qt = sw & 15, h = (sw >> 4) & 7, b = sw >> 7;
  const int q0 = qt*128 + w*32;
  bf16x8 aq[2][4];                           // Q[q = q0+h2*16+lr][kk*32+lh*8]
  const u16* qbase = qs + ((size_t)(b*Hh + h)*Ss + q0 + lr)*QD + lh*8;
#pragma unroll
  for (int h2 = 0; h2 < 2; h2++)
#pragma unroll
    for (int kk = 0; kk < 4; kk++)
      aq[h2][kk] = *(const bf16x8*)(qbase + (size_t)h2*16*QD + kk*32);
  float m[2] = {-INFINITY, -INFINITY}, sume[2] = {0.f, 0.f};
  f32x4 acc[2][12] = {};
  const char* ksrc0 = (const char*)(ks + (size_t)b*Ss*KD);
  const char* vsrc0 = (const char*)(vt + (size_t)b*VD*Ss);
  for (int kv0 = 0; kv0 < Ss; kv0 += 64) {
    // ---- stage K (16KB, contiguous) + V^T (24KB, 128B rows) ----
    {
      const char* ksrc = ksrc0 + (size_t)kv0*KD*2;
#pragma unroll
      for (int r = 0; r < 4; r++) {
        int o = r*4096 + w*1024 + l*16;
        gload16(ksrc + (o ^ (((o>>8)&7)<<4)), (char*)k_lds + r*4096 + w*1024);
      }
#pragma unroll
      for (int r = 0; r < 6; r++) {
        int o = r*4096 + w*1024 + l*16;
        int vd = o >> 7, c = o & 127;
        gload16(vsrc0 + (size_t)vd*(Ss*2) + kv0*2 + (c ^ ((vd&7)<<4)),
                (char*)v_lds + r*4096 + w*1024);
      }
    }
    __syncthreads();                         // drains vmcnt -> tiles valid
    // ---- S^T = K @ Q^T : 64kv x 32q, K frags shared across q-halves ----
    f32x4 sv[2][4] = {};
#pragma unroll
    for (int nt = 0; nt < 4; nt++) {
#pragma unroll
      for (int kk = 0; kk < 4; kk++) {
        int kb = ((nt*16 + lr) << 8) + kk*64 + lh*16;
        kb ^= (lr & 7) << 4;
        bf16x8 bk = *(const bf16x8*)((const char*)k_lds + kb);
        sv[0][nt] = mfma16(bk, aq[0][kk], sv[0][nt]);
        sv[1][nt] = mfma16(bk, aq[1][kk], sv[1][nt]);
      }
    }
    // ---- lane-local online softmax per q-half (T13 defer-max) ----
#pragma unroll
    for (int h2 = 0; h2 < 2; h2++) {
      float tmx = -INFINITY;
#pragma unroll
      for (int nt = 0; nt < 4; nt++)
        tmx = fmaxf(tmx, fmaxf(fmaxf(sv[h2][nt][0], sv[h2][nt][1]),
                               fmaxf(sv[h2][nt][2], sv[h2][nt][3])));
      tmx = fmaxf(tmx, __shfl_xor(tmx, 16));
      tmx = fmaxf(tmx, __shfl_xor(tmx, 32));
      if (!__all(tmx - m[h2] <= 8.f)) {
        float mnew = fmaxf(m[h2], tmx);
        float scl = __expf(m[h2] - mnew);
        m[h2] = mnew; sume[h2] *= scl;
#pragma unroll
        for (int n = 0; n < 12; n++) acc[h2][n] *= scl;
      }
      float tsum = 0.f;
#pragma unroll
      for (int nt = 0; nt < 4; nt++) {
#pragma unroll
        for (int r2 = 0; r2 < 4; r2++) {
          float e = __expf(sv[h2][nt][r2] - m[h2]);
          sv[h2][nt][r2] = e; tsum += e;
        }
      }
      tsum += __shfl_xor(tsum, 16);
      tsum += __shfl_xor(tsum, 32);
      sume[h2] += tsum;
      {                                      // P -> LDS, packed b32, XOR-swizzled
        char* pw = (char*)&p_lds[w][h2*16 + lr][0];
#pragma unroll
        for (int nt = 0; nt < 4; nt++) {
          u32 w0 = cvtpk(sv[h2][nt][0], sv[h2][nt][1]);
          u32 w1 = cvtpk(sv[h2][nt][2], sv[h2][nt][3]);
          int pcol = (nt*32 + lh*8) ^ ((lr & 7) << 4);
          *(u32*)(pw + pcol)     = w0;
          *(u32*)(pw + pcol + 4) = w1;
        }
      }
    }
    asm volatile("s_waitcnt lgkmcnt(0)" ::: "memory");  // wave-local P visible
    __builtin_amdgcn_sched_barrier(0);
    // ---- O^T += V^T @ P ; V frags shared across q-halves ----
#pragma unroll
    for (int kk2 = 0; kk2 < 2; kk2++) {
      int rcol = (kk2*64 + lh*16) ^ ((lr & 7) << 4);
      bf16x8 pb0 = *(const bf16x8*)((const char*)&p_lds[w][lr][0]      + rcol);
      bf16x8 pb1 = *(const bf16x8*)((const char*)&p_lds[w][16 + lr][0] + rcol);
#pragma unroll
      for (int n = 0; n < 12; n++) {
        int vb = ((n*16 + lr) << 7) + kk2*64 + lh*16;
        vb ^= (lr & 7) << 4;
        bf16x8 av = *(const bf16x8*)((const char*)v_lds + vb);
        acc[0][n] = mfma16(av, pb0, acc[0][n]);
        acc[1][n] = mfma16(av, pb1, acc[1][n]);
      }
    }
    __syncthreads();                         // WAR: reads done before next stage
  }
#pragma unroll
  for (int h2 = 0; h2 < 2; h2++) {
    float inv = 1.f / sume[h2];
#pragma unroll
    for (int n = 0; n < 12; n++) {           // O[q][vd], packed 8B store
      u32 w0 = cvtpk(acc[h2][n][0]*inv, acc[h2][n][1]*inv);
      u32 w1 = cvtpk(acc[h2][n][2]*inv, acc[h2][n][3]*inv);
      size_t o = ((size_t)b*Ss + q0 + h2*16 + lr)*Cc + h*VD + n*16 + lh*4;
      *(uint2*)(O + o) = make_uint2(w0, w1);
    }
  }
}

extern "C" void kernel_launch(void* const* d_in, const int* in_sizes, int n_in,
                              void* d_out, int out_size, void* d_ws, size_t ws_size,
                              hipStream_t stream)
{
  const float* x     = (const float*)d_in[0];
  const float* rms_g = (const float*)d_in[1];
  const float* rms_b = (const float*)d_in[2];
  const float* rms_r = (const float*)d_in[3];
  const float* Wq    = (const float*)d_in[4];
  const float* Wk    = (const float*)d_in[5];
  const float* Wv    = (const float*)d_in[6];
  const float* q_g   = (const float*)d_in[7];
  const float* q_b   = (const float*)d_in[8];
  const float* k_g   = (const float*)d_in[9];
  const float* k_b   = (const float*)d_in[10];
  const float* v_g   = (const float*)d_in[11];
  const float* v_b   = (const float*)d_in[12];
  const float* Wo    = (const float*)d_in[13];
  const float* bo    = (const float*)d_in[14];
  const float* on_g  = (const float*)d_in[15];
  const float* on_b  = (const float*)d_in[16];
  const float* on_r  = (const float*)d_in[17];
  char* ws = (char*)d_ws;

  k_prep_small<<<dim3((Cc + Ss*64 + Ss*96) / 256), 256, 0, stream>>>(
      rms_g, rms_b, rms_r, on_g, on_b, on_r, bo, ws);
  k_prep_w<<<dim3(2048), 256, 0, stream>>>(Wq, Wk, Wv, Wo, ws);
  k_xn<<<dim3(NTOK*Cc/4/256), 256, 0, stream>>>(x, ws);
  k_gemm256<false><<<dim3(NQKV_PAD/256, NTOK/256), 512, 0, stream>>>(
      (const u16*)(ws + OFF_XN), (const u16*)(ws + OFF_WQKV), (void*)(ws + OFF_QKV),
      Cc, NQKV, nullptr, nullptr);
  k_lnrope_qk<<<dim3((NTOK*Hh + NTOK)/4), 256, 0, stream>>>(ws, q_g, q_b, k_g, k_b);
  k_lnrope_v<<<dim3(NTOK/4), 256, 0, stream>>>(ws, v_g, v_b);
  k_attn<<<dim3(Bb*Hh*(Ss/128)), 256, 0, stream>>>(ws, (u16*)(ws + OFF_XN));
  k_gemm256<true><<<dim3(Cc/256, NTOK/256), 512, 0, stream>>>(
      (const u16*)(ws + OFF_XN), (const u16*)(ws + OFF_WO), d_out,
      Cc, Cc, (const float*)(ws + OFF_S2), (const float*)(ws + OFF_B2));
}

// Round 6
// 357.269 us; speedup vs baseline: 2.8847x; 1.0470x over previous
//
#include <hip/hip_runtime.h>
#include <math.h>

typedef unsigned short u16;
typedef unsigned int   u32;
typedef __attribute__((ext_vector_type(8))) short bf16x8;   // 8 bf16 (4 VGPRs)
typedef __attribute__((ext_vector_type(4))) float f32x4;

#define DEVI static __device__ __forceinline__

// ---- problem dims ----
constexpr int Bb = 4, Ss = 2048, Cc = 1536, Hh = 8, QD = 128, KD = 128, VD = 192;
constexpr int NTOK = Bb * Ss;              // 8192 tokens
constexpr int NQKV = Hh*QD + KD + VD;      // 1344
constexpr int NQKV_PAD = 1536;             // padded to 6*256 for 256^2 GEMM tiles
constexpr float ATTN_SCALE = 0.08838834764831845f;  // 1/sqrt(128), folded into q

// ---- workspace layout (bytes); total ~84 MB ----
constexpr size_t OFF_S1  = 0;                               // f32[C] rms scale
constexpr size_t OFF_B1  = OFF_S1 + Cc*4;                   // f32[C] rms shift
constexpr size_t OFF_S2  = OFF_B1 + Cc*4;                   // f32[C] out-bn scale
constexpr size_t OFF_B2  = OFF_S2 + Cc*4;                   // f32[C] bo*s2+on_b
constexpr size_t OFF_CT  = 24576;                           // cos qk [S][64]
constexpr size_t OFF_ST  = OFF_CT  + (size_t)Ss*64*4;       // sin qk
constexpr size_t OFF_CTV = OFF_ST  + (size_t)Ss*64*4;       // cos v [S][96]
constexpr size_t OFF_STV = OFF_CTV + (size_t)Ss*96*4;       // sin v
constexpr size_t OFF_WQKV= OFF_STV + (size_t)Ss*96*4;       // bf16 [1536][1536] (rows>=1344 zero)
constexpr size_t OFF_WO  = OFF_WQKV+ (size_t)NQKV_PAD*Cc*2; // bf16 [1536][1536]
constexpr size_t OFF_XN  = OFF_WO  + (size_t)Cc*Cc*2;       // bf16 [8192][1536]; REUSED as attn O
constexpr size_t OFF_QKV = OFF_XN  + (size_t)NTOK*Cc*2;     // bf16 [8192][1344]
constexpr size_t OFF_Q   = OFF_QKV + (size_t)NTOK*NQKV*2;   // bf16 [B][H][S][128] (rope'd, scaled)
constexpr size_t OFF_K   = OFF_Q   + (size_t)NTOK*(Hh*QD)*2;// bf16 [B][S][128]
constexpr size_t OFF_VT  = OFF_K   + (size_t)NTOK*KD*2;     // bf16 [B][192][S]  (V transposed)

DEVI u16 f2b(float f) {            // f32 -> bf16 RTNE
  union { float f; u32 u; } v; v.f = f;
  u32 r = v.u + 0x7FFFu + ((v.u >> 16) & 1u);
  return (u16)(r >> 16);
}
DEVI float b2f(u16 h) {
  union { u32 u; float f; } v; v.u = ((u32)h) << 16;
  return v.f;
}
DEVI u32 cvtpk(float lo, float hi) {       // 2 f32 -> packed bf16x2 (RTNE)
  u32 r;
  asm("v_cvt_pk_bf16_f32 %0, %1, %2" : "=v"(r) : "v"(lo), "v"(hi));
  return r;
}
DEVI void gload16(const void* g, void* l) {   // async global->LDS, 16B/lane
  __builtin_amdgcn_global_load_lds(g, l, 16, 0, 0);
}
DEVI f32x4 mfma16(bf16x8 a, bf16x8 b, f32x4 c) {
  return __builtin_amdgcn_mfma_f32_16x16x32_bf16(a, b, c, 0, 0, 0);
}

// ===== prep: per-channel scales + rope tables =====
__global__ __launch_bounds__(256) void k_prep_small(
    const float* __restrict__ rms_g, const float* __restrict__ rms_b, const float* __restrict__ rms_r,
    const float* __restrict__ on_g,  const float* __restrict__ on_b,  const float* __restrict__ on_r,
    const float* __restrict__ bo, char* __restrict__ ws)
{
  int i = blockIdx.x * 256 + threadIdx.x;
  float* s1 = (float*)(ws + OFF_S1);
  float* b1 = (float*)(ws + OFF_B1);
  float* s2 = (float*)(ws + OFF_S2);
  float* b2 = (float*)(ws + OFF_B2);
  float* ct = (float*)(ws + OFF_CT);
  float* st = (float*)(ws + OFF_ST);
  float* ctv= (float*)(ws + OFF_CTV);
  float* stv= (float*)(ws + OFF_STV);
  if (i < Cc) {
    float a = rsqrtf(rms_r[i] + 1e-6f) * rms_g[i];
    s1[i] = a; b1[i] = rms_b[i];
    float c = rsqrtf(on_r[i] + 1e-6f) * on_g[i];
    s2[i] = c; b2[i] = bo[i]*c + on_b[i];
  }
  int j = i - Cc;
  if (j >= 0 && j < Ss*64) {            // qk tables, half=64
    int s = j >> 6, f = j & 63;
    float invf = expf(-(float)f * (9.210340371976184f / 64.f)); // 10000^(-f/64)
    float ang = (float)s * invf;
    float sn, cs; sincosf(ang, &sn, &cs);
    ct[j] = cs; st[j] = sn;
  }
  int k = j - Ss*64;
  if (k >= 0 && k < Ss*96) {            // v tables, half=96
    int s = k / 96, f = k - s*96;
    float invf = expf(-(float)f * (9.210340371976184f / 96.f));
    float ang = (float)s * invf;
    float sn, cs; sincosf(ang, &sn, &cs);
    ctv[k] = cs; stv[k] = sn;
  }
}

// ===== prep: weights -> bf16, vectorized x4 (Wqkv concat + zero-pad rows >=1344) =====
__global__ __launch_bounds__(256) void k_prep_w(
    const float* __restrict__ Wq, const float* __restrict__ Wk, const float* __restrict__ Wv,
    const float* __restrict__ Wo, char* __restrict__ ws)
{
  u16* wqkv = (u16*)(ws + OFF_WQKV);
  u16* wo   = (u16*)(ws + OFF_WO);
  const int total1 = NQKV_PAD * Cc / 4;      // float4 groups
  const int total2 = Cc * Cc / 4;
  for (int i = blockIdx.x*256 + threadIdx.x; i < total1 + total2; i += gridDim.x*256) {
    float4 v = make_float4(0.f, 0.f, 0.f, 0.f);
    u16* dst;
    if (i < total1) {
      int r = i / 384, c = (i - r*384) * 4;        // Cc/4 = 384
      if (r < 1024)      v = *(const float4*)&Wq[(size_t)r*Cc + c];
      else if (r < 1152) v = *(const float4*)&Wk[(size_t)(r-1024)*Cc + c];
      else if (r < 1344) v = *(const float4*)&Wv[(size_t)(r-1152)*Cc + c];
      dst = wqkv + (size_t)i*4;
    } else {
      int t2 = i - total1;
      v = *(const float4*)&Wo[(size_t)t2*4];
      dst = wo + (size_t)t2*4;
    }
    u32 lo = (u32)f2b(v.x) | ((u32)f2b(v.y) << 16);
    u32 hi = (u32)f2b(v.z) | ((u32)f2b(v.w) << 16);
    *(uint2*)dst = make_uint2(lo, hi);
  }
}

// ===== xn = x*s1 + b1 (rms_batchnorm is elementwise), f32 -> bf16 =====
__global__ __launch_bounds__(256) void k_xn(const float* __restrict__ x, char* __restrict__ ws)
{
  const float* s1 = (const float*)(ws + OFF_S1);
  const float* b1 = (const float*)(ws + OFF_B1);
  u16* xn = (u16*)(ws + OFF_XN);
  int idx = blockIdx.x*256 + threadIdx.x;          // one float4 per thread, exact grid
  float4 xv = ((const float4*)x)[idx];
  int c = (idx % (Cc/4)) * 4;
  u32 lo = (u32)f2b(xv.x*s1[c]   + b1[c])   | ((u32)f2b(xv.y*s1[c+1] + b1[c+1]) << 16);
  u32 hi = (u32)f2b(xv.z*s1[c+2] + b1[c+2]) | ((u32)f2b(xv.w*s1[c+3] + b1[c+3]) << 16);
  ((uint2*)xn)[idx] = make_uint2(lo, hi);
}

// ===== 256x256 BT-GEMM, BK=64, 2-tile dbuf, 4-phase counted-vmcnt pipeline =====
// A[M][K] bf16, B[N][K] bf16, K=1536.  8 waves (2M x 4N), per-wave out 128x64.
// Per tile (BK=64): 4 quadrant phases x 16 MFMA, snake frag reuse (24 ds_read/tile),
// 2 gload-calls of tile t+1 per phase, vmcnt(2) once per tile (never 0 mid-loop).
// LDS XOR swizzle: byte ^= (row&7)<<4 on 128B rows; staged via pre-swizzled SOURCE.
template <bool EPI>
__global__ __launch_bounds__(512) void k_gemm256(
    const u16* __restrict__ A, const u16* __restrict__ Bw, void* __restrict__ outp,
    int K_, int N_store, const float* __restrict__ s2, const float* __restrict__ b2)
{
  __shared__ u16 tiles[2][2][256*64];   // [buf][A|B][256 rows x 64 k], 128 KiB
  constexpr int K = Cc;                 // 1536 (both GEMMs)
  constexpr int NT = K / 64;            // 24 K-tiles
  constexpr size_t Kb = (size_t)K * 2;  // 3072 B row stride
  const int tid = threadIdx.x;
  const int wid = tid >> 6, l = tid & 63;
  const int lr = l & 15, lh = l >> 4;
  const int wr = wid >> 2, wc = wid & 3;
  // bijective XCD chunk swizzle (nwg = 192 = 8 * 24)
  const int id  = blockIdx.x + gridDim.x * blockIdx.y;
  const int cpx = (gridDim.x * gridDim.y) >> 3;
  const int sw  = (id & 7) * cpx + (id >> 3);
  const int by  = sw / gridDim.x;
  const int bx  = sw - by * gridDim.x;
  const int m0 = by * 256, n0 = bx * 256;

  // ---- staging addressing (pre-swizzled global source, linear LDS dest) ----
  // chunk c in 0..7: region A (c<4) / B (c>=4), rows (c&3)*64 + tid/8,
  // source col byte = ((tid&7)^( (tid>>3)&7 ))<<4  (inverse of read-side XOR)
  const int tid8 = tid >> 3;
  const int csrc = (((tid & 7) ^ (tid8 & 7)) << 4);
  const char* aS = (const char*)A  + (size_t)(m0 + tid8) * Kb + csrc;
  const char* bS = (const char*)Bw + (size_t)(n0 + tid8) * Kb + csrc;
  char* ldsW = (char*)&tiles[0][0][0] + wid*1024;   // wave-uniform dest base

#define STAGE2(bf, t, c0_) {                                                   \
    gload16(((c0_) < 4 ? aS : bS) + (size_t)((c0_)&3)*64*Kb + (size_t)(t)*128, \
            ldsW + (bf)*65536 + ((c0_) < 4 ? 0 : 32768) + ((c0_)&3)*8192);     \
    gload16((((c0_)+1) < 4 ? aS : bS) + (size_t)(((c0_)+1)&3)*64*Kb + (size_t)(t)*128, \
            ldsW + (bf)*65536 + (((c0_)+1) < 4 ? 0 : 32768) + (((c0_)+1)&3)*8192); }

  // ---- fragment read bases (XOR folded; mi*2048 / ni*2048 become ds imm offsets) ----
  const int swz = (lr & 7) << 4;
  int baseA[2], baseB[2];
#pragma unroll
  for (int ks = 0; ks < 2; ks++) {
    baseA[ks] = (((wr*128 + lr) * 128) + ks*64 + lh*16) ^ swz;
    baseB[ks] = (((wc*64  + lr) * 128) + ks*64 + lh*16) ^ swz;
  }

  f32x4 acc[8][4] = {};
  bf16x8 fa[4][2], fb0[2][2], fb1[2][2];

  // ---- prologue: stage tile 0 fully (8 calls) ----
  STAGE2(0, 0, 0); STAGE2(0, 0, 2); STAGE2(0, 0, 4); STAGE2(0, 0, 6);

#pragma unroll 1
  for (int t = 0; t < NT; ++t) {
    const int buf = t & 1, nbuf = buf ^ 1;
    const char* la = (const char*)&tiles[buf][0][0];
    const char* lb = (const char*)&tiles[buf][1][0];
    // ===== phase 0: quadrant (m0-3, n0-1) =====
    if (t + 1 < NT) {
      STAGE2(nbuf, t+1, 0);
      asm volatile("s_waitcnt vmcnt(2)" ::: "memory");   // tile t landed; 2 in flight
    } else {
      asm volatile("s_waitcnt vmcnt(0)" ::: "memory");   // last tile: drain
    }
    __builtin_amdgcn_s_barrier();
#pragma unroll
    for (int mi = 0; mi < 4; mi++)
#pragma unroll
      for (int ks = 0; ks < 2; ks++)
        fa[mi][ks] = *(const bf16x8*)(la + baseA[ks] + mi*2048);
#pragma unroll
    for (int ni = 0; ni < 2; ni++)
#pragma unroll
      for (int ks = 0; ks < 2; ks++)
        fb0[ni][ks] = *(const bf16x8*)(lb + baseB[ks] + ni*2048);
    __builtin_amdgcn_s_setprio(1);
#pragma unroll
    for (int mi = 0; mi < 4; mi++)
#pragma unroll
      for (int ni = 0; ni < 2; ni++)
#pragma unroll
        for (int ks = 0; ks < 2; ks++)
          acc[mi][ni] = mfma16(fa[mi][ks], fb0[ni][ks], acc[mi][ni]);
    __builtin_amdgcn_s_setprio(0);
    __builtin_amdgcn_s_barrier();
    // ===== phase 1: quadrant (m0-3, n2-3), reuse fa =====
#pragma unroll
    for (int ni = 0; ni < 2; ni++)
#pragma unroll
      for (int ks = 0; ks < 2; ks++)
        fb1[ni][ks] = *(const bf16x8*)(lb + baseB[ks] + (2+ni)*2048);
    if (t + 1 < NT) STAGE2(nbuf, t+1, 2);
    __builtin_amdgcn_s_barrier();
    __builtin_amdgcn_s_setprio(1);
#pragma unroll
    for (int mi = 0; mi < 4; mi++)
#pragma unroll
      for (int ni = 0; ni < 2; ni++)
#pragma unroll
        for (int ks = 0; ks < 2; ks++)
          acc[mi][2+ni] = mfma16(fa[mi][ks], fb1[ni][ks], acc[mi][2+ni]);
    __builtin_amdgcn_s_setprio(0);
    __builtin_amdgcn_s_barrier();
    // ===== phase 2: quadrant (m4-7, n2-3), reuse fb1 =====
#pragma unroll
    for (int mi = 0; mi < 4; mi++)
#pragma unroll
      for (int ks = 0; ks < 2; ks++)
        fa[mi][ks] = *(const bf16x8*)(la + baseA[ks] + (4+mi)*2048);
    if (t + 1 < NT) STAGE2(nbuf, t+1, 4);
    __builtin_amdgcn_s_barrier();
    __builtin_amdgcn_s_setprio(1);
#pragma unroll
    for (int mi = 0; mi < 4; mi++)
#pragma unroll
      for (int ni = 0; ni < 2; ni++)
#pragma unroll
        for (int ks = 0; ks < 2; ks++)
          acc[4+mi][2+ni] = mfma16(fa[mi][ks], fb1[ni][ks], acc[4+mi][2+ni]);
    __builtin_amdgcn_s_setprio(0);
    __builtin_amdgcn_s_barrier();
    // ===== phase 3: quadrant (m4-7, n0-1), reuse fa + fb0 (no reads) =====
    if (t + 1 < NT) STAGE2(nbuf, t+1, 6);
    __builtin_amdgcn_s_barrier();
    __builtin_amdgcn_s_setprio(1);
#pragma unroll
    for (int mi = 0; mi < 4; mi++)
#pragma unroll
      for (int ni = 0; ni < 2; ni++)
#pragma unroll
        for (int ks = 0; ks < 2; ks++)
          acc[4+mi][ni] = mfma16(fa[mi][ks], fb0[ni][ks], acc[4+mi][ni]);
    __builtin_amdgcn_s_setprio(0);
    __builtin_amdgcn_s_barrier();
  }
#undef STAGE2

  const int r0 = m0 + wr*128 + lh*4;
  const int c0 = n0 + wc*64 + lr;
#pragma unroll
  for (int mi = 0; mi < 8; mi++) {
#pragma unroll
    for (int ni = 0; ni < 4; ni++) {
      int col = c0 + ni*16;
      if (col < N_store) {
#pragma unroll
        for (int r = 0; r < 4; r++) {
          size_t o = (size_t)(r0 + mi*16 + r) * N_store + col;
          if (EPI) ((float*)outp)[o] = acc[mi][ni][r] * s2[col] + b2[col];
          else     ((u16*)outp)[o]   = f2b(acc[mi][ni][r]);
        }
      }
    }
  }
}

// ===== fused LayerNorm + RoPE for q (65536 rows) and k (8192 rows), 1 wave/row =====
__global__ __launch_bounds__(256) void k_lnrope_qk(
    char* __restrict__ ws,
    const float* __restrict__ q_g, const float* __restrict__ q_b,
    const float* __restrict__ k_g, const float* __restrict__ k_b)
{
  const u16* qkv = (const u16*)(ws + OFF_QKV);
  u16* qo = (u16*)(ws + OFF_Q);
  u16* ko = (u16*)(ws + OFF_K);
  const float* ct = (const float*)(ws + OFF_CT);
  const float* st = (const float*)(ws + OFF_ST);
  const int w = threadIdx.x >> 6, l = threadIdx.x & 63;
  const int rid = blockIdx.x*4 + w;
  const u16* src; u16* dst; const float* g; const float* bb; float osc; int s;
  if (rid < NTOK*Hh) {                       // q rows, order t*8+h
    int t = rid >> 3, h = rid & 7;
    s = t & (Ss-1); int b = t >> 11;
    src = qkv + (size_t)t*NQKV + h*QD;
    dst = qo + ((size_t)(b*Hh + h)*Ss + s)*QD;
    g = q_g; bb = q_b; osc = ATTN_SCALE;
  } else {                                   // k rows
    int t = rid - NTOK*Hh;
    s = t & (Ss-1);
    src = qkv + (size_t)t*NQKV + Hh*QD;
    dst = ko + (size_t)t*KD;
    g = k_g; bb = k_b; osc = 1.f;
  }
  u32 pk = *(const u32*)(src + 2*l);         // elems 2l, 2l+1
  float x0 = b2f((u16)(pk & 0xFFFFu)), x1 = b2f((u16)(pk >> 16));
  float sm = x0 + x1, sq = x0*x0 + x1*x1;
#pragma unroll
  for (int off = 1; off < 64; off <<= 1) { sm += __shfl_xor(sm, off); sq += __shfl_xor(sq, off); }
  float mean = sm * (1.f/128.f);
  float var  = sq * (1.f/128.f) - mean*mean;
  float rstd = rsqrtf(var + 1e-5f);
  int d0 = 2*l;
  float y0 = (x0 - mean)*rstd*g[d0]   + bb[d0];
  float y1 = (x1 - mean)*rstd*g[d0+1] + bb[d0+1];
  float z0 = __shfl_xor(y0, 32);             // rope partner (d <-> d+64)
  float z1 = __shfl_xor(y1, 32);
  int f0 = 2*(l & 31);
  float c0 = ct[s*64 + f0],     s0 = st[s*64 + f0];
  float c1 = ct[s*64 + f0 + 1], s1 = st[s*64 + f0 + 1];
  float o0, o1;
  if (l < 32) { o0 = y0*c0 - z0*s0; o1 = y1*c1 - z1*s1; }   // x1*cos - x2*sin
  else        { o0 = z0*s0 + y0*c0; o1 = z1*s1 + y1*c1; }   // x1*sin + x2*cos
  o0 *= osc; o1 *= osc;
  *(u32*)(dst + 2*l) = (u32)f2b(o0) | ((u32)f2b(o1) << 16);
}

// ===== fused LayerNorm + RoPE for v (192 dims), writes V TRANSPOSED [b][d][s] =====
__global__ __launch_bounds__(256) void k_lnrope_v(
    char* __restrict__ ws, const float* __restrict__ v_g, const float* __restrict__ v_b)
{
  const u16* qkv = (const u16*)(ws + OFF_QKV);
  u16* vo = (u16*)(ws + OFF_VT);
  const float* ct = (const float*)(ws + OFF_CTV);
  const float* st = (const float*)(ws + OFF_STV);
  __shared__ float buf[4][192];
  const int w = threadIdx.x >> 6, l = threadIdx.x & 63;
  const int t = blockIdx.x*4 + w;
  const int s = t & (Ss-1), b = t >> 11;
  const u16* src = qkv + (size_t)t*NQKV + Hh*QD + KD;
  float xs[3]; float sm = 0.f, sq = 0.f;
#pragma unroll
  for (int i2 = 0; i2 < 3; i2++) {
    float xv = b2f(src[l + 64*i2]);
    xs[i2] = xv; buf[w][l + 64*i2] = xv;
    sm += xv; sq += xv*xv;
  }
  __threadfence_block();                     // make row visible (same-wave LDS ordering)
#pragma unroll
  for (int off = 1; off < 64; off <<= 1) { sm += __shfl_xor(sm, off); sq += __shfl_xor(sq, off); }
  float mean = sm * (1.f/192.f);
  float var  = sq * (1.f/192.f) - mean*mean;
  float rstd = rsqrtf(var + 1e-5f);
#pragma unroll
  for (int i2 = 0; i2 < 3; i2++) {
    int e = l + 64*i2;
    float val;
    if (e < 96) {
      float x1 = xs[i2], x2 = buf[w][e+96];
      float x1n = (x1-mean)*rstd*v_g[e]    + v_b[e];
      float x2n = (x2-mean)*rstd*v_g[e+96] + v_b[e+96];
      float cs = ct[s*96 + e], sn = st[s*96 + e];
      val = x1n*cs - x2n*sn;
    } else {
      int f = e - 96;
      float x2 = xs[i2], x1 = buf[w][f];
      float x1n = (x1-mean)*rstd*v_g[f] + v_b[f];
      float x2n = (x2-mean)*rstd*v_g[e] + v_b[e];
      float cs = ct[s*96 + f], sn = st[s*96 + f];
      val = x1n*sn + x2n*cs;
    }
    vo[((size_t)b*VD + e)*Ss + s] = f2b(val);
  }
}

// ===== flash attention v3: LDS-staged K/V tiles, swapped QK^T, QBLK=128 =====
__global__ __launch_bounds__(256, 2) void k_attn(const char* __restrict__ ws, u16* __restrict__ O)
{
  const u16* qs = (const u16*)(ws + OFF_Q);
  const u16* ks = (const u16*)(ws + OFF_K);
  const u16* vt = (const u16*)(ws + OFF_VT);
  __shared__ u16 k_lds[64*128];              // [kv][d], 256B rows, swizzled
  __shared__ u16 v_lds[192*64];              // [vd][kv], 128B rows, swizzled
  __shared__ u16 p_lds[4][32][64];           // P[q][kv], 128B rows, XOR-swizzled
  const int tid = threadIdx.x, w = tid >> 6, l = tid & 63;
  const int lr = l & 15, lh = l >> 4;
  const int bid0 = blockIdx.x;
  const int sw = (bid0 & 7)*64 + (bid0 >> 3);   // XCD swizzle: each XCD -> one b
  const int qt = sw & 15, h = (sw >> 4) & 7, b = sw >> 7;
  const int q0 = qt*128 + w*32;
  bf16x8 aq[2][4];                           // Q[q = q0+h2*16+lr][kk*32+lh*8]
  const u16* qbase = qs + ((size_t)(b*Hh + h)*Ss + q0 + lr)*QD + lh*8;
#pragma unroll
  for (int h2 = 0; h2 < 2; h2++)
#pragma unroll
    for (int kk = 0; kk < 4; kk++)
      aq[h2][kk] = *(const bf16x8*)(qbase + (size_t)h2*16*QD + kk*32);
  float m[2] = {-INFINITY, -INFINITY}, sume[2] = {0.f, 0.f};
  f32x4 acc[2][12] = {};
  const char* ksrc0 = (const char*)(ks + (size_t)b*Ss*KD);
  const char* vsrc0 = (const char*)(vt + (size_t)b*VD*Ss);
  for (int kv0 = 0; kv0 < Ss; kv0 += 64) {
    // ---- stage K (16KB, contiguous) + V^T (24KB, 128B rows) ----
    {
      const char* ksrc = ksrc0 + (size_t)kv0*KD*2;
#pragma unroll
      for (int r = 0; r < 4; r++) {
        int o = r*4096 + w*1024 + l*16;
        gload16(ksrc + (o ^ (((o>>8)&7)<<4)), (char*)k_lds + r*4096 + w*1024);
      }
#pragma unroll
      for (int r = 0; r < 6; r++) {
        int o = r*4096 + w*1024 + l*16;
        int vd = o >> 7, c = o & 127;
        gload16(vsrc0 + (size_t)vd*(Ss*2) + kv0*2 + (c ^ ((vd&7)<<4)),
                (char*)v_lds + r*4096 + w*1024);
      }
    }
    __syncthreads();                         // drains vmcnt -> tiles valid
    // ---- S^T = K @ Q^T : 64kv x 32q, K frags shared across q-halves ----
    f32x4 sv[2][4] = {};
#pragma unroll
    for (int nt = 0; nt < 4; nt++) {
#pragma unroll
      for (int kk = 0; kk < 4; kk++) {
        int kb = ((nt*16 + lr) << 8) + kk*64 + lh*16;
        kb ^= (lr & 7) << 4;
        bf16x8 bk = *(const bf16x8*)((const char*)k_lds + kb);
        sv[0][nt] = mfma16(bk, aq[0][kk], sv[0][nt]);
        sv[1][nt] = mfma16(bk, aq[1][kk], sv[1][nt]);
      }
    }
    // ---- lane-local online softmax per q-half (T13 defer-max) ----
#pragma unroll
    for (int h2 = 0; h2 < 2; h2++) {
      float tmx = -INFINITY;
#pragma unroll
      for (int nt = 0; nt < 4; nt++)
        tmx = fmaxf(tmx, fmaxf(fmaxf(sv[h2][nt][0], sv[h2][nt][1]),
                               fmaxf(sv[h2][nt][2], sv[h2][nt][3])));
      tmx = fmaxf(tmx, __shfl_xor(tmx, 16));
      tmx = fmaxf(tmx, __shfl_xor(tmx, 32));
      if (!__all(tmx - m[h2] <= 8.f)) {
        float mnew = fmaxf(m[h2], tmx);
        float scl = __expf(m[h2] - mnew);
        m[h2] = mnew; sume[h2] *= scl;
#pragma unroll
        for (int n = 0; n < 12; n++) acc[h2][n] *= scl;
      }
      float tsum = 0.f;
#pragma unroll
      for (int nt = 0; nt < 4; nt++) {
#pragma unroll
        for (int r2 = 0; r2 < 4; r2++) {
          float e = __expf(sv[h2][nt][r2] - m[h2]);
          sv[h2][nt][r2] = e; tsum += e;
        }
      }
      tsum += __shfl_xor(tsum, 16);
      tsum += __shfl_xor(tsum, 32);
      sume[h2] += tsum;
      {                                      // P -> LDS, packed b32, XOR-swizzled
        char* pw = (char*)&p_lds[w][h2*16 + lr][0];
#pragma unroll
        for (int nt = 0; nt < 4; nt++) {
          u32 w0 = cvtpk(sv[h2][nt][0], sv[h2][nt][1]);
          u32 w1 = cvtpk(sv[h2][nt][2], sv[h2][nt][3]);
          int pcol = (nt*32 + lh*8) ^ ((lr & 7) << 4);
          *(u32*)(pw + pcol)     = w0;
          *(u32*)(pw + pcol + 4) = w1;
        }
      }
    }
    asm volatile("s_waitcnt lgkmcnt(0)" ::: "memory");  // wave-local P visible
    __builtin_amdgcn_sched_barrier(0);
    // ---- O^T += V^T @ P ; V frags shared across q-halves ----
#pragma unroll
    for (int kk2 = 0; kk2 < 2; kk2++) {
      int rcol = (kk2*64 + lh*16) ^ ((lr & 7) << 4);
      bf16x8 pb0 = *(const bf16x8*)((const char*)&p_lds[w][lr][0]      + rcol);
      bf16x8 pb1 = *(const bf16x8*)((const char*)&p_lds[w][16 + lr][0] + rcol);
#pragma unroll
      for (int n = 0; n < 12; n++) {
        int vb = ((n*16 + lr) << 7) + kk2*64 + lh*16;
        vb ^= (lr & 7) << 4;
        bf16x8 av = *(const bf16x8*)((const char*)v_lds + vb);
        acc[0][n] = mfma16(av, pb0, acc[0][n]);
        acc[1][n] = mfma16(av, pb1, acc[1][n]);
      }
    }
    __syncthreads();                         // WAR: reads done before next stage
  }
#pragma unroll
  for (int h2 = 0; h2 < 2; h2++) {
    float inv = 1.f / sume[h2];
#pragma unroll
    for (int n = 0; n < 12; n++) {           // O[q][vd], packed 8B store
      u32 w0 = cvtpk(acc[h2][n][0]*inv, acc[h2][n][1]*inv);
      u32 w1 = cvtpk(acc[h2][n][2]*inv, acc[h2][n][3]*inv);
      size_t o = ((size_t)b*Ss + q0 + h2*16 + lr)*Cc + h*VD + n*16 + lh*4;
      *(uint2*)(O + o) = make_uint2(w0, w1);
    }
  }
}

extern "C" void kernel_launch(void* const* d_in, const int* in_sizes, int n_in,
                              void* d_out, int out_size, void* d_ws, size_t ws_size,
                              hipStream_t stream)
{
  const float* x     = (const float*)d_in[0];
  const float* rms_g = (const float*)d_in[1];
  const float* rms_b = (const float*)d_in[2];
  const float* rms_r = (const float*)d_in[3];
  const float* Wq    = (const float*)d_in[4];
  const float* Wk    = (const float*)d_in[5];
  const float* Wv    = (const float*)d_in[6];
  const float* q_g   = (const float*)d_in[7];
  const float* q_b   = (const float*)d_in[8];
  const float* k_g   = (const float*)d_in[9];
  const float* k_b   = (const float*)d_in[10];
  const float* v_g   = (const float*)d_in[11];
  const float* v_b   = (const float*)d_in[12];
  const float* Wo    = (const float*)d_in[13];
  const float* bo    = (const float*)d_in[14];
  const float* on_g  = (const float*)d_in[15];
  const float* on_b  = (const float*)d_in[16];
  const float* on_r  = (const float*)d_in[17];
  char* ws = (char*)d_ws;

  k_prep_small<<<dim3((Cc + Ss*64 + Ss*96) / 256), 256, 0, stream>>>(
      rms_g, rms_b, rms_r, on_g, on_b, on_r, bo, ws);
  k_prep_w<<<dim3(1536), 256, 0, stream>>>(Wq, Wk, Wv, Wo, ws);
  k_xn<<<dim3(NTOK*Cc/4/256), 256, 0, stream>>>(x, ws);
  k_gemm256<false><<<dim3(NQKV_PAD/256, NTOK/256), 512, 0, stream>>>(
      (const u16*)(ws + OFF_XN), (const u16*)(ws + OFF_WQKV), (void*)(ws + OFF_QKV),
      Cc, NQKV, nullptr, nullptr);
  k_lnrope_qk<<<dim3((NTOK*Hh + NTOK)/4), 256, 0, stream>>>(ws, q_g, q_b, k_g, k_b);
  k_lnrope_v<<<dim3(NTOK/4), 256, 0, stream>>>(ws, v_g, v_b);
  k_attn<<<dim3(Bb*Hh*(Ss/128)), 256, 0, stream>>>(ws, (u16*)(ws + OFF_XN));
  k_gemm256<true><<<dim3(Cc/256, NTOK/256), 512, 0, stream>>>(
      (const u16*)(ws + OFF_XN), (const u16*)(ws + OFF_WO), d_out,
      Cc, Cc, (const float*)(ws + OFF_S2), (const float*)(ws + OFF_B2));
}